// Round 7
// baseline (234.846 us; speedup 1.0000x reference)
//
#include <hip/hip_runtime.h>

static constexpr int DIN = 64;
static constexpr int H1  = 256;
static constexpr int H2  = 128;

using half8 = _Float16 __attribute__((ext_vector_type(8)));
using f32x4 = float __attribute__((ext_vector_type(4)));

// ---------------- zero int buffer ----------------
__global__ void k_zero(int* __restrict__ ptr, int n) {
  int i = blockIdx.x * blockDim.x + threadIdx.x;
  if (i < n) ptr[i] = 0;
}

// ---------------- degree histogram + per-edge rank ----------------
__global__ void k_hist(const int* __restrict__ dst, int* __restrict__ hist,
                       unsigned short* __restrict__ rank, int E) {
  int e = blockIdx.x * blockDim.x + threadIdx.x;
  if (e < E) {
    int old = atomicAdd(&hist[dst[e]], 1);
    rank[e] = (unsigned short)old;
  }
}

__global__ void k_dinv(const int* __restrict__ hist, float* __restrict__ dinv, int N) {
  int i = blockIdx.x * blockDim.x + threadIdx.x;
  if (i < N) dinv[i] = rsqrtf((float)hist[i] + 1.0f);   // +1 self-loop
}

// ---------------- hierarchical exclusive scan: hist[N] -> offs[N+1] ----------------
__global__ void k_scan1(const int* __restrict__ hist, int* __restrict__ offs,
                        int* __restrict__ bsum, int N) {
  __shared__ int ws[4];
  const int t = threadIdx.x;
  const int base = blockIdx.x * 1024 + t * 4;
  int4 v = make_int4(0, 0, 0, 0);
  if (base + 3 < N) v = *(const int4*)(hist + base);
  else {
    if (base + 0 < N) v.x = hist[base + 0];
    if (base + 1 < N) v.y = hist[base + 1];
    if (base + 2 < N) v.z = hist[base + 2];
    if (base + 3 < N) v.w = hist[base + 3];
  }
  int tsum = v.x + v.y + v.z + v.w;
  int lane = t & 63, wid = t >> 6;
  int incl = tsum;
#pragma unroll
  for (int off = 1; off < 64; off <<= 1) {
    int u = __shfl_up(incl, off);
    if (lane >= off) incl += u;
  }
  if (lane == 63) ws[wid] = incl;
  __syncthreads();
  int wbase = 0;
  for (int w = 0; w < wid; ++w) wbase += ws[w];
  int excl = wbase + incl - tsum;
  int4 o;
  o.x = excl;
  o.y = excl + v.x;
  o.z = excl + v.x + v.y;
  o.w = excl + v.x + v.y + v.z;
  if (base + 3 < N) *(int4*)(offs + base) = o;
  else {
    if (base + 0 < N) offs[base + 0] = o.x;
    if (base + 1 < N) offs[base + 1] = o.y;
    if (base + 2 < N) offs[base + 2] = o.z;
    if (base + 3 < N) offs[base + 3] = o.w;
  }
  if (t == 255) bsum[blockIdx.x] = wbase + incl;
}

__global__ void k_scan2(int* __restrict__ bsum, int* __restrict__ offs,
                        int nb, int N, int E) {
  int t = threadIdx.x;
  int v = (t < nb) ? bsum[t] : 0;
  int incl = v;
#pragma unroll
  for (int off = 1; off < 64; off <<= 1) {
    int u = __shfl_up(incl, off);
    if (t >= off) incl += u;
  }
  if (t < nb) bsum[t] = incl - v;
  if (t == 0) offs[N] = E;
}

__global__ void k_scan3(int* __restrict__ offs, const int* __restrict__ bsum, int N) {
  if (blockIdx.x == 0) return;
  int b = bsum[blockIdx.x];
  int base = blockIdx.x * 1024 + threadIdx.x * 4;
  if (base + 3 < N) {
    int4 v = *(int4*)(offs + base);
    v.x += b; v.y += b; v.z += b; v.w += b;
    *(int4*)(offs + base) = v;
  } else {
    for (int k = 0; k < 4; ++k) if (base + k < N) offs[base + k] += b;
  }
}

// ---------------- atomic-free CSR build (u16 payload) ----------------
__global__ void k_build(const int* __restrict__ src, const int* __restrict__ dst,
                        const unsigned short* __restrict__ rank,
                        const int* __restrict__ offs,
                        unsigned short* __restrict__ csr, int E) {
  int e = blockIdx.x * blockDim.x + threadIdx.x;
  if (e < E) {
    int d = dst[e];
    int pos = offs[d] + (int)rank[e];
    __builtin_nontemporal_store((unsigned short)src[e], &csr[pos]);
  }
}

// ---------------- cast fp32 -> fp16, vector 8 ----------------
__global__ void k_cast(const float* __restrict__ x, _Float16* __restrict__ xh, int nvec8) {
  int i = blockIdx.x * blockDim.x + threadIdx.x;
  if (i < nvec8) {
    const float4* x4 = (const float4*)x;
    float4 a = x4[i * 2 + 0];
    float4 b = x4[i * 2 + 1];
    half8 h;
    h[0] = (_Float16)a.x; h[1] = (_Float16)a.y; h[2] = (_Float16)a.z; h[3] = (_Float16)a.w;
    h[4] = (_Float16)b.x; h[5] = (_Float16)b.y; h[6] = (_Float16)b.z; h[7] = (_Float16)b.w;
    *(half8*)(xh + (size_t)i * 8) = h;
  }
}

// ---------------- W[K][NOUT] fp32 -> B-fragment-ordered fp16 table ----------------
template<int K, int NOUT>
__global__ void k_wfrag(const float* __restrict__ W, _Float16* __restrict__ Wf) {
  int i = blockIdx.x * blockDim.x + threadIdx.x;
  if (i >= K * NOUT) return;
  int j    = i & 7;
  int lane = (i >> 3) & 63;
  int rest = i >> 9;
  int t    = rest % (K / 32);
  int c    = rest / (K / 32);
  int k    = t * 32 + (lane >> 4) * 8 + j;
  int col  = c * 16 + (lane & 15);
  Wf[i] = (_Float16)W[k * NOUT + col];
}

// ---------------- fused head weights: Wz = W2 @ [nW | eWtop | eWbot], consts ----------------
__global__ void k_wz(const float* __restrict__ W2, const float* __restrict__ nW,
                     const float* __restrict__ nb, const float* __restrict__ eW,
                     const float* __restrict__ b2,
                     float* __restrict__ Wz, float* __restrict__ consts) {
  int k = threadIdx.x;  // 256 threads, 1 block
  float acc[6] = {0, 0, 0, 0, 0, 0};
  for (int m = 0; m < H2; ++m) {
    float w = W2[k * H2 + m];
    acc[0] = fmaf(w, nW[m * 2 + 0], acc[0]);
    acc[1] = fmaf(w, nW[m * 2 + 1], acc[1]);
    acc[2] = fmaf(w, eW[m * 2 + 0], acc[2]);
    acc[3] = fmaf(w, eW[m * 2 + 1], acc[3]);
    acc[4] = fmaf(w, eW[(H2 + m) * 2 + 0], acc[4]);
    acc[5] = fmaf(w, eW[(H2 + m) * 2 + 1], acc[5]);
  }
#pragma unroll
  for (int c = 0; c < 6; ++c) Wz[k * 8 + c] = acc[c];
  Wz[k * 8 + 6] = 0.0f; Wz[k * 8 + 7] = 0.0f;
  if (k == 0) {
    float c0 = nb[0], c1 = nb[1], c2 = 0, c3 = 0, c4 = 0, c5 = 0;
    for (int m = 0; m < H2; ++m) {
      float b = b2[m];
      c0 = fmaf(b, nW[m * 2 + 0], c0);
      c1 = fmaf(b, nW[m * 2 + 1], c1);
      c2 = fmaf(b, eW[m * 2 + 0], c2);
      c3 = fmaf(b, eW[m * 2 + 1], c3);
      c4 = fmaf(b, eW[(H2 + m) * 2 + 0], c4);
      c5 = fmaf(b, eW[(H2 + m) * 2 + 1], c5);
    }
    consts[0] = c0; consts[1] = c1; consts[2] = c2;
    consts[3] = c3; consts[4] = c4; consts[5] = c5;
    consts[6] = 0.0f; consts[7] = 0.0f;
  }
}

// ---------------- MFMA GEMM: C[M,NOUT] = A[M,K] @ W[K,NOUT], fused bias+relu ----------------
template<int K, int NOUT, bool BIAS, bool RELU>
__global__ __launch_bounds__(256) void
k_mgemm(const _Float16* __restrict__ A, const _Float16* __restrict__ Wf,
        const float* __restrict__ bias, _Float16* __restrict__ C, int M) {
  constexpr int NC = NOUT / 16;
  constexpr int NT = K / 32;
  const int wave = threadIdx.x >> 6;
  const int lane = threadIdx.x & 63;
  const int rowbase = blockIdx.x * 128 + wave * 32;
  if (rowbase >= M) return;
  const int r  = lane & 15;
  const int kb = lane >> 4;
  int row0 = rowbase + r;       if (row0 >= M) row0 = M - 1;
  int row1 = rowbase + 16 + r;  if (row1 >= M) row1 = M - 1;
  const _Float16* a0p = A + (size_t)row0 * K + kb * 8;
  const _Float16* a1p = A + (size_t)row1 * K + kb * 8;

  f32x4 acc[2][NC];
#pragma unroll
  for (int rb = 0; rb < 2; ++rb)
#pragma unroll
    for (int c = 0; c < NC; ++c) acc[rb][c] = (f32x4)0.0f;

#pragma unroll
  for (int t = 0; t < NT; ++t) {
    half8 a0 = *(const half8*)(a0p + t * 32);
    half8 a1 = *(const half8*)(a1p + t * 32);
#pragma unroll
    for (int c = 0; c < NC; ++c) {
      half8 bf = ((const half8*)Wf)[(size_t)(c * NT + t) * 64 + lane];
      acc[0][c] = __builtin_amdgcn_mfma_f32_16x16x32_f16(a0, bf, acc[0][c], 0, 0, 0);
      acc[1][c] = __builtin_amdgcn_mfma_f32_16x16x32_f16(a1, bf, acc[1][c], 0, 0, 0);
    }
  }

#pragma unroll
  for (int rb = 0; rb < 2; ++rb) {
    int growbase = rowbase + rb * 16 + kb * 4;
#pragma unroll
    for (int c = 0; c < NC; ++c) {
      int col = c * 16 + r;
      float bv = BIAS ? bias[col] : 0.0f;
#pragma unroll
      for (int j = 0; j < 4; ++j) {
        int grow = growbase + j;
        if (grow < M) {
          float v = acc[rb][c][j] + bv;
          if (RELU) v = fmaxf(v, 0.0f);
          C[(size_t)grow * NOUT + col] = (_Float16)v;
        }
      }
    }
  }
}

// ---------------- CSR gather (fp16 payload, fp32 accumulate) ----------------
template<int C, bool BIAS>
__global__ __launch_bounds__(256) void
k_gather(const int* __restrict__ offs, const unsigned short* __restrict__ csr,
         const float* __restrict__ dinv, const _Float16* __restrict__ xw,
         const float* __restrict__ bias, _Float16* __restrict__ out, int N) {
  constexpr int GSIZE = C / 8;
  constexpr int NE    = 64 / GSIZE;
  int wave = (int)((blockIdx.x * (size_t)blockDim.x + threadIdx.x) >> 6);
  int lane = threadIdx.x & 63;
  if (wave >= N) return;
  int group = lane / GSIZE;
  int sub   = lane % GSIZE;
  int ch0   = sub * 8;
  float dv = dinv[wave];
  int j0 = offs[wave], j1 = offs[wave + 1];

  float acc[8];
  if (group == 0) {
    half8 v = *(const half8*)(xw + (size_t)wave * C + ch0);
    float sc = dv * dv;
#pragma unroll
    for (int k = 0; k < 8; ++k) acc[k] = (float)v[k] * sc;
  } else {
#pragma unroll
    for (int k = 0; k < 8; ++k) acc[k] = 0.0f;
  }

  for (int base = j0; base < j1; base += 64) {
    int myj = base + lane;
    int s_l = 0; float dv_l = 0.0f;
    if (myj < j1) { s_l = (int)csr[myj]; dv_l = dinv[s_l]; }
    int cnt = min(64, j1 - base);
    for (int k = 0; k < cnt; k += NE) {
      int idx = k + group;
      int   s = __shfl(s_l, idx);
      float c = __shfl(dv_l, idx) * dv;
      half8 v = *(const half8*)(xw + (size_t)s * C + ch0);
#pragma unroll
      for (int k2 = 0; k2 < 8; ++k2) acc[k2] = fmaf((float)v[k2], c, acc[k2]);
    }
  }

#pragma unroll
  for (int off = GSIZE; off < 64; off <<= 1) {
#pragma unroll
    for (int k = 0; k < 8; ++k) acc[k] += __shfl_xor(acc[k], off);
  }

  if (group == 0) {
    half8 o;
#pragma unroll
    for (int k = 0; k < 8; ++k) {
      float v = acc[k] + (BIAS ? bias[ch0 + k] : 0.0f);
      o[k] = (_Float16)v;
    }
    *(half8*)(out + (size_t)wave * C + ch0) = o;
  }
}

// ---------------- z = h @ Wz : 4 threads per node, 64 channels each ----------------
__global__ __launch_bounds__(256) void
k_z(const _Float16* __restrict__ h, const float* __restrict__ Wz,
    float* __restrict__ z, int N) {
  int t = (int)(blockIdx.x * (size_t)blockDim.x + threadIdx.x);
  int node = t >> 2;
  int sub  = t & 3;
  if (node >= N) return;
  int ch0 = sub * 64;
  const half8* hp = (const half8*)(h + (size_t)node * H1 + ch0);
  float zc[6] = {0, 0, 0, 0, 0, 0};
#pragma unroll
  for (int v = 0; v < 8; ++v) {
    half8 hv = hp[v];
#pragma unroll
    for (int j = 0; j < 8; ++j) {
      float a = (float)hv[j];
      const float4* wr = (const float4*)(Wz + (ch0 + v * 8 + j) * 8);
      float4 w0 = wr[0];
      float4 w1 = wr[1];
      zc[0] = fmaf(a, w0.x, zc[0]);
      zc[1] = fmaf(a, w0.y, zc[1]);
      zc[2] = fmaf(a, w0.z, zc[2]);
      zc[3] = fmaf(a, w0.w, zc[3]);
      zc[4] = fmaf(a, w1.x, zc[4]);
      zc[5] = fmaf(a, w1.y, zc[5]);
    }
  }
#pragma unroll
  for (int off = 1; off < 4; off <<= 1) {
#pragma unroll
    for (int c = 0; c < 6; ++c) zc[c] += __shfl_xor(zc[c], off);
  }
  if (sub == 0) {
    float4 lo = make_float4(zc[0], zc[1], zc[2], zc[3]);
    float4 hi = make_float4(zc[4], zc[5], 0.0f, 0.0f);
    *(float4*)(z + (size_t)node * 8)     = lo;
    *(float4*)(z + (size_t)node * 8 + 4) = hi;
  }
}

// ---------------- aggregate z (C=8 fp32) -> node_out, p, q ----------------
__global__ __launch_bounds__(256) void
k_gatherz(const int* __restrict__ offs, const unsigned short* __restrict__ csr,
          const float* __restrict__ dinv, const float* __restrict__ z,
          const float* __restrict__ consts,
          float* __restrict__ node_out, float* __restrict__ p, float* __restrict__ q,
          int N) {
  int wave = (int)((blockIdx.x * (size_t)blockDim.x + threadIdx.x) >> 6);
  int lane = threadIdx.x & 63;
  if (wave >= N) return;
  int group = lane >> 1;     // 32 edge-groups
  int sub   = lane & 1;      // which float4 half of the row
  float dv = dinv[wave];
  int j0 = offs[wave], j1 = offs[wave + 1];

  float4 acc = make_float4(0.0f, 0.0f, 0.0f, 0.0f);
  if (group == 0) {
    float4 v = *(const float4*)(z + (size_t)wave * 8 + sub * 4);
    float sc = dv * dv;
    acc = make_float4(v.x * sc, v.y * sc, v.z * sc, v.w * sc);
  }

  for (int base = j0; base < j1; base += 64) {
    int myj = base + lane;
    int s_l = 0; float dv_l = 0.0f;
    if (myj < j1) { s_l = (int)csr[myj]; dv_l = dinv[s_l]; }
    int cnt = min(64, j1 - base);
    for (int k = 0; k < cnt; k += 32) {
      int idx = k + group;
      int   s = __shfl(s_l, idx);
      float c = __shfl(dv_l, idx) * dv;
      float4 v = *(const float4*)(z + (size_t)s * 8 + sub * 4);
      acc.x = fmaf(v.x, c, acc.x);
      acc.y = fmaf(v.y, c, acc.y);
      acc.z = fmaf(v.z, c, acc.z);
      acc.w = fmaf(v.w, c, acc.w);
    }
  }

#pragma unroll
  for (int off = 2; off < 64; off <<= 1) {
    acc.x += __shfl_xor(acc.x, off);
    acc.y += __shfl_xor(acc.y, off);
    acc.z += __shfl_xor(acc.z, off);
    acc.w += __shfl_xor(acc.w, off);
  }

  if (lane == 0) {            // channels 0..3: node_x(2), p(2)
    float2 no = make_float2(acc.x + consts[0], acc.y + consts[1]);
    float2 pp = make_float2(acc.z + consts[2], acc.w + consts[3]);
    *(float2*)(node_out + (size_t)wave * 2) = no;
    *(float2*)(p + (size_t)wave * 2) = pp;
  } else if (lane == 1) {     // channels 4..7: q(2)
    float2 qq = make_float2(acc.x + consts[4], acc.y + consts[5]);
    *(float2*)(q + (size_t)wave * 2) = qq;
  }
}

// ---------------- edge output ----------------
__global__ void k_edge(const int* __restrict__ src, const int* __restrict__ dst,
                       const float* __restrict__ p, const float* __restrict__ q,
                       const float* __restrict__ eb, float* __restrict__ eout, int E) {
  int e = blockIdx.x * blockDim.x + threadIdx.x;
  if (e < E) {
    int s = src[e], d = dst[e];
    float2 P = *reinterpret_cast<const float2*>(p + (size_t)s * 2);
    float2 Q = *reinterpret_cast<const float2*>(q + (size_t)d * 2);
    float2 o;
    o.x = P.x + Q.x + eb[0];
    o.y = P.y + Q.y + eb[1];
    *reinterpret_cast<float2*>(eout + (size_t)e * 2) = o;
  }
}

extern "C" void kernel_launch(void* const* d_in, const int* in_sizes, int n_in,
                              void* d_out, int out_size, void* d_ws, size_t ws_size,
                              hipStream_t stream) {
  const float* x   = (const float*)d_in[0];
  const int*   ei  = (const int*)d_in[1];
  const float* W1  = (const float*)d_in[2];
  const float* b1  = (const float*)d_in[3];
  const float* W2  = (const float*)d_in[4];
  const float* b2  = (const float*)d_in[5];
  const float* nW  = (const float*)d_in[6];
  const float* nb  = (const float*)d_in[7];
  const float* eW  = (const float*)d_in[8];
  const float* eb  = (const float*)d_in[9];

  const int N = in_sizes[0] / DIN;   // 50000
  const int E = in_sizes[1] / 2;     // 800000
  const int* src = ei;
  const int* dst = ei + E;

  // ---- workspace layout ----
  float* fws   = (float*)d_ws;
  float* dinv  = fws;                            // N
  float* p     = dinv + N;                       // 2N
  float* q     = p + 2 * (size_t)N;              // 2N
  float* z     = q + 2 * (size_t)N;              // 8N
  float* Wz    = z + 8 * (size_t)N;              // 2048
  float* consts = Wz + 2048;                     // 8
  _Float16* xh    = (_Float16*)(consts + 8);     // 64N
  _Float16* aggxh = xh + (size_t)DIN * N;        // 64N
  _Float16* h     = aggxh + (size_t)DIN * N;     // 256N
  _Float16* Wf1   = h + (size_t)H1 * N;          // DIN*H1 = 16384
  int* hist = (int*)(Wf1 + DIN * H1);            // N
  int* offs = hist + N;                          // N+1
  int* bsum = offs + N + 1;                      // 64 (pad to keep alignment)
  unsigned short* rank = (unsigned short*)(bsum + 64);   // E
  unsigned short* csr  = rank + E;                        // E

  float* node_out = (float*)d_out;                   // 2N
  float* edge_out = (float*)d_out + 2 * (size_t)N;   // 2E

  const int nb_blk = (N + 1023) / 1024;

  // ---- CSR build ----
  k_zero<<<(N + 255) / 256, 256, 0, stream>>>(hist, N);
  k_hist<<<(E + 255) / 256, 256, 0, stream>>>(dst, hist, rank, E);
  k_dinv<<<(N + 255) / 256, 256, 0, stream>>>(hist, dinv, N);
  k_scan1<<<nb_blk, 256, 0, stream>>>(hist, offs, bsum, N);
  k_scan2<<<1, 64, 0, stream>>>(bsum, offs, nb_blk, N, E);
  k_scan3<<<nb_blk, 256, 0, stream>>>(offs, bsum, N);
  k_build<<<(E + 255) / 256, 256, 0, stream>>>(src, dst, rank, offs, csr, E);

  // ---- weight prep + x cast ----
  k_wfrag<DIN, H1><<<(DIN * H1 + 255) / 256, 256, 0, stream>>>(W1, Wf1);
  k_wz<<<1, 256, 0, stream>>>(W2, nW, nb, eW, b2, Wz, consts);
  k_cast<<<((N * DIN / 8) + 255) / 256, 256, 0, stream>>>(x, xh, N * DIN / 8);

  // ---- layer 1: aggregate-then-transform ----
  k_gather<DIN, false><<<(N + 3) / 4, 256, 0, stream>>>(offs, csr, dinv, xh, nullptr, aggxh, N);
  k_mgemm<DIN, H1, true, true><<<(N + 127) / 128, 256, 0, stream>>>(aggxh, Wf1, b1, h, N);

  // ---- fused layer-2 + heads: z = h@Wz (4 thr/node), aggregate 6-dim z ----
  k_z<<<((N * 4) + 255) / 256, 256, 0, stream>>>(h, Wz, z, N);
  k_gatherz<<<(N + 3) / 4, 256, 0, stream>>>(offs, csr, dinv, z, consts, node_out, p, q, N);

  // ---- edge output ----
  k_edge<<<(E + 255) / 256, 256, 0, stream>>>(src, dst, p, q, eb, edge_out, E);
}

// Round 8
// 183.633 us; speedup vs baseline: 1.2789x; 1.2789x over previous
//
#include <hip/hip_runtime.h>

static constexpr int DIN = 64;
static constexpr int H1  = 256;
static constexpr int H2  = 128;

using half8 = _Float16 __attribute__((ext_vector_type(8)));
using f32x4 = float __attribute__((ext_vector_type(4)));

// ---------------- zero int buffer ----------------
__global__ void k_zero(int* __restrict__ ptr, int n) {
  int i = blockIdx.x * blockDim.x + threadIdx.x;
  if (i < n) ptr[i] = 0;
}

// ---------------- degree histogram + per-edge rank ----------------
__global__ void k_hist(const int* __restrict__ dst, int* __restrict__ hist,
                       unsigned short* __restrict__ rank, int E) {
  int e = blockIdx.x * blockDim.x + threadIdx.x;
  if (e < E) {
    int old = atomicAdd(&hist[dst[e]], 1);
    rank[e] = (unsigned short)old;
  }
}

__global__ void k_dinv(const int* __restrict__ hist, float* __restrict__ dinv, int N) {
  int i = blockIdx.x * blockDim.x + threadIdx.x;
  if (i < N) dinv[i] = rsqrtf((float)hist[i] + 1.0f);   // +1 self-loop
}

// ---------------- hierarchical exclusive scan: hist[N] -> offs[N+1] ----------------
__global__ void k_scan1(const int* __restrict__ hist, int* __restrict__ offs,
                        int* __restrict__ bsum, int N) {
  __shared__ int ws[4];
  const int t = threadIdx.x;
  const int base = blockIdx.x * 1024 + t * 4;
  int4 v = make_int4(0, 0, 0, 0);
  if (base + 3 < N) v = *(const int4*)(hist + base);
  else {
    if (base + 0 < N) v.x = hist[base + 0];
    if (base + 1 < N) v.y = hist[base + 1];
    if (base + 2 < N) v.z = hist[base + 2];
    if (base + 3 < N) v.w = hist[base + 3];
  }
  int tsum = v.x + v.y + v.z + v.w;
  int lane = t & 63, wid = t >> 6;
  int incl = tsum;
#pragma unroll
  for (int off = 1; off < 64; off <<= 1) {
    int u = __shfl_up(incl, off);
    if (lane >= off) incl += u;
  }
  if (lane == 63) ws[wid] = incl;
  __syncthreads();
  int wbase = 0;
  for (int w = 0; w < wid; ++w) wbase += ws[w];
  int excl = wbase + incl - tsum;
  int4 o;
  o.x = excl;
  o.y = excl + v.x;
  o.z = excl + v.x + v.y;
  o.w = excl + v.x + v.y + v.z;
  if (base + 3 < N) *(int4*)(offs + base) = o;
  else {
    if (base + 0 < N) offs[base + 0] = o.x;
    if (base + 1 < N) offs[base + 1] = o.y;
    if (base + 2 < N) offs[base + 2] = o.z;
    if (base + 3 < N) offs[base + 3] = o.w;
  }
  if (t == 255) bsum[blockIdx.x] = wbase + incl;
}

__global__ void k_scan2(int* __restrict__ bsum, int* __restrict__ offs,
                        int nb, int N, int E) {
  int t = threadIdx.x;
  int v = (t < nb) ? bsum[t] : 0;
  int incl = v;
#pragma unroll
  for (int off = 1; off < 64; off <<= 1) {
    int u = __shfl_up(incl, off);
    if (t >= off) incl += u;
  }
  if (t < nb) bsum[t] = incl - v;
  if (t == 0) offs[N] = E;
}

__global__ void k_scan3(int* __restrict__ offs, const int* __restrict__ bsum, int N) {
  if (blockIdx.x == 0) return;
  int b = bsum[blockIdx.x];
  int base = blockIdx.x * 1024 + threadIdx.x * 4;
  if (base + 3 < N) {
    int4 v = *(int4*)(offs + base);
    v.x += b; v.y += b; v.z += b; v.w += b;
    *(int4*)(offs + base) = v;
  } else {
    for (int k = 0; k < 4; ++k) if (base + k < N) offs[base + k] += b;
  }
}

// ---------------- atomic-free CSR build (u16 payload) ----------------
__global__ void k_build(const int* __restrict__ src, const int* __restrict__ dst,
                        const unsigned short* __restrict__ rank,
                        const int* __restrict__ offs,
                        unsigned short* __restrict__ csr, int E) {
  int e = blockIdx.x * blockDim.x + threadIdx.x;
  if (e < E) {
    int d = dst[e];
    int pos = offs[d] + (int)rank[e];
    __builtin_nontemporal_store((unsigned short)src[e], &csr[pos]);
  }
}

// ---------------- cast fp32 -> fp16, vector 8 ----------------
__global__ void k_cast(const float* __restrict__ x, _Float16* __restrict__ xh, int nvec8) {
  int i = blockIdx.x * blockDim.x + threadIdx.x;
  if (i < nvec8) {
    const float4* x4 = (const float4*)x;
    float4 a = x4[i * 2 + 0];
    float4 b = x4[i * 2 + 1];
    half8 h;
    h[0] = (_Float16)a.x; h[1] = (_Float16)a.y; h[2] = (_Float16)a.z; h[3] = (_Float16)a.w;
    h[4] = (_Float16)b.x; h[5] = (_Float16)b.y; h[6] = (_Float16)b.z; h[7] = (_Float16)b.w;
    *(half8*)(xh + (size_t)i * 8) = h;
  }
}

// ---------------- W[K][NOUT] fp32 -> B-fragment-ordered fp16 table ----------------
template<int K, int NOUT>
__global__ void k_wfrag(const float* __restrict__ W, _Float16* __restrict__ Wf) {
  int i = blockIdx.x * blockDim.x + threadIdx.x;
  if (i >= K * NOUT) return;
  int j    = i & 7;
  int lane = (i >> 3) & 63;
  int rest = i >> 9;
  int t    = rest % (K / 32);
  int c    = rest / (K / 32);
  int k    = t * 32 + (lane >> 4) * 8 + j;
  int col  = c * 16 + (lane & 15);
  Wf[i] = (_Float16)W[k * NOUT + col];
}

// ---------------- fused head weights: Wzp[256,16] = W2 @ [nW|eWtop|eWbot] padded ----------------
__global__ void k_wz(const float* __restrict__ W2, const float* __restrict__ nW,
                     const float* __restrict__ nb, const float* __restrict__ eW,
                     const float* __restrict__ b2,
                     float* __restrict__ Wzp, float* __restrict__ consts) {
  int k = threadIdx.x;  // 256 threads, 1 block
  float acc[6] = {0, 0, 0, 0, 0, 0};
  for (int m = 0; m < H2; ++m) {
    float w = W2[k * H2 + m];
    acc[0] = fmaf(w, nW[m * 2 + 0], acc[0]);
    acc[1] = fmaf(w, nW[m * 2 + 1], acc[1]);
    acc[2] = fmaf(w, eW[m * 2 + 0], acc[2]);
    acc[3] = fmaf(w, eW[m * 2 + 1], acc[3]);
    acc[4] = fmaf(w, eW[(H2 + m) * 2 + 0], acc[4]);
    acc[5] = fmaf(w, eW[(H2 + m) * 2 + 1], acc[5]);
  }
#pragma unroll
  for (int c = 0; c < 6; ++c) Wzp[k * 16 + c] = acc[c];
#pragma unroll
  for (int c = 6; c < 16; ++c) Wzp[k * 16 + c] = 0.0f;
  if (k == 0) {
    float c0 = nb[0], c1 = nb[1], c2 = 0, c3 = 0, c4 = 0, c5 = 0;
    for (int m = 0; m < H2; ++m) {
      float b = b2[m];
      c0 = fmaf(b, nW[m * 2 + 0], c0);
      c1 = fmaf(b, nW[m * 2 + 1], c1);
      c2 = fmaf(b, eW[m * 2 + 0], c2);
      c3 = fmaf(b, eW[m * 2 + 1], c3);
      c4 = fmaf(b, eW[(H2 + m) * 2 + 0], c4);
      c5 = fmaf(b, eW[(H2 + m) * 2 + 1], c5);
    }
    consts[0] = c0; consts[1] = c1; consts[2] = c2;
    consts[3] = c3; consts[4] = c4; consts[5] = c5;
    consts[6] = 0.0f; consts[7] = 0.0f;
  }
}

// ---------------- MFMA GEMM: C[M,NOUT] = A[M,K] @ W[K,NOUT], fused bias+relu ----------------
template<int K, int NOUT, bool BIAS, bool RELU>
__global__ __launch_bounds__(256) void
k_mgemm(const _Float16* __restrict__ A, const _Float16* __restrict__ Wf,
        const float* __restrict__ bias, _Float16* __restrict__ C, int M) {
  constexpr int NC = NOUT / 16;
  constexpr int NT = K / 32;
  const int wave = threadIdx.x >> 6;
  const int lane = threadIdx.x & 63;
  const int rowbase = blockIdx.x * 128 + wave * 32;
  if (rowbase >= M) return;
  const int r  = lane & 15;
  const int kb = lane >> 4;
  int row0 = rowbase + r;       if (row0 >= M) row0 = M - 1;
  int row1 = rowbase + 16 + r;  if (row1 >= M) row1 = M - 1;
  const _Float16* a0p = A + (size_t)row0 * K + kb * 8;
  const _Float16* a1p = A + (size_t)row1 * K + kb * 8;

  f32x4 acc[2][NC];
#pragma unroll
  for (int rb = 0; rb < 2; ++rb)
#pragma unroll
    for (int c = 0; c < NC; ++c) acc[rb][c] = (f32x4)0.0f;

#pragma unroll
  for (int t = 0; t < NT; ++t) {
    half8 a0 = *(const half8*)(a0p + t * 32);
    half8 a1 = *(const half8*)(a1p + t * 32);
#pragma unroll
    for (int c = 0; c < NC; ++c) {
      half8 bf = ((const half8*)Wf)[(size_t)(c * NT + t) * 64 + lane];
      acc[0][c] = __builtin_amdgcn_mfma_f32_16x16x32_f16(a0, bf, acc[0][c], 0, 0, 0);
      acc[1][c] = __builtin_amdgcn_mfma_f32_16x16x32_f16(a1, bf, acc[1][c], 0, 0, 0);
    }
  }

#pragma unroll
  for (int rb = 0; rb < 2; ++rb) {
    int growbase = rowbase + rb * 16 + kb * 4;
#pragma unroll
    for (int c = 0; c < NC; ++c) {
      int col = c * 16 + r;
      float bv = BIAS ? bias[col] : 0.0f;
#pragma unroll
      for (int j = 0; j < 4; ++j) {
        int grow = growbase + j;
        if (grow < M) {
          float v = acc[rb][c][j] + bv;
          if (RELU) v = fmaxf(v, 0.0f);
          C[(size_t)grow * NOUT + col] = (_Float16)v;
        }
      }
    }
  }
}

// ---------------- MFMA z-GEMM: z[M,8] = h[M,256] @ Wzf[256,16] (cols 0..7 stored) ----------------
__global__ __launch_bounds__(256) void
k_mgemmz(const _Float16* __restrict__ A, const _Float16* __restrict__ Wf,
         float* __restrict__ z, int M) {
  constexpr int K = H1, NT = K / 32;
  const int wave = threadIdx.x >> 6;
  const int lane = threadIdx.x & 63;
  const int rowbase = blockIdx.x * 128 + wave * 32;
  if (rowbase >= M) return;
  const int r  = lane & 15;
  const int kb = lane >> 4;
  int row0 = rowbase + r;       if (row0 >= M) row0 = M - 1;
  int row1 = rowbase + 16 + r;  if (row1 >= M) row1 = M - 1;
  const _Float16* a0p = A + (size_t)row0 * K + kb * 8;
  const _Float16* a1p = A + (size_t)row1 * K + kb * 8;

  f32x4 acc0 = (f32x4)0.0f, acc1 = (f32x4)0.0f;
#pragma unroll
  for (int t = 0; t < NT; ++t) {
    half8 a0 = *(const half8*)(a0p + t * 32);
    half8 a1 = *(const half8*)(a1p + t * 32);
    half8 bf = ((const half8*)Wf)[(size_t)t * 64 + lane];
    acc0 = __builtin_amdgcn_mfma_f32_16x16x32_f16(a0, bf, acc0, 0, 0, 0);
    acc1 = __builtin_amdgcn_mfma_f32_16x16x32_f16(a1, bf, acc1, 0, 0, 0);
  }

  if (r < 8) {
#pragma unroll
    for (int j = 0; j < 4; ++j) {
      int g0 = rowbase + kb * 4 + j;
      if (g0 < M) z[(size_t)g0 * 8 + r] = acc0[j];
      int g1 = rowbase + 16 + kb * 4 + j;
      if (g1 < M) z[(size_t)g1 * 8 + r] = acc1[j];
    }
  }
}

// ---------------- CSR gather (fp16 payload, fp32 accumulate) ----------------
template<int C, bool BIAS>
__global__ __launch_bounds__(256) void
k_gather(const int* __restrict__ offs, const unsigned short* __restrict__ csr,
         const float* __restrict__ dinv, const _Float16* __restrict__ xw,
         const float* __restrict__ bias, _Float16* __restrict__ out, int N) {
  constexpr int GSIZE = C / 8;
  constexpr int NE    = 64 / GSIZE;
  int wave = (int)((blockIdx.x * (size_t)blockDim.x + threadIdx.x) >> 6);
  int lane = threadIdx.x & 63;
  if (wave >= N) return;
  int group = lane / GSIZE;
  int sub   = lane % GSIZE;
  int ch0   = sub * 8;
  float dv = dinv[wave];
  int j0 = offs[wave], j1 = offs[wave + 1];

  float acc[8];
  if (group == 0) {
    half8 v = *(const half8*)(xw + (size_t)wave * C + ch0);
    float sc = dv * dv;
#pragma unroll
    for (int k = 0; k < 8; ++k) acc[k] = (float)v[k] * sc;
  } else {
#pragma unroll
    for (int k = 0; k < 8; ++k) acc[k] = 0.0f;
  }

  for (int base = j0; base < j1; base += 64) {
    int myj = base + lane;
    int s_l = 0; float dv_l = 0.0f;
    if (myj < j1) { s_l = (int)csr[myj]; dv_l = dinv[s_l]; }
    int cnt = min(64, j1 - base);
    for (int k = 0; k < cnt; k += NE) {
      int idx = k + group;
      int   s = __shfl(s_l, idx);
      float c = __shfl(dv_l, idx) * dv;
      half8 v = *(const half8*)(xw + (size_t)s * C + ch0);
#pragma unroll
      for (int k2 = 0; k2 < 8; ++k2) acc[k2] = fmaf((float)v[k2], c, acc[k2]);
    }
  }

#pragma unroll
  for (int off = GSIZE; off < 64; off <<= 1) {
#pragma unroll
    for (int k = 0; k < 8; ++k) acc[k] += __shfl_xor(acc[k], off);
  }

  if (group == 0) {
    half8 o;
#pragma unroll
    for (int k = 0; k < 8; ++k) {
      float v = acc[k] + (BIAS ? bias[ch0 + k] : 0.0f);
      o[k] = (_Float16)v;
    }
    *(half8*)(out + (size_t)wave * C + ch0) = o;
  }
}

// ---------------- aggregate z (C=8 fp32) -> node_out, p, q ----------------
__global__ __launch_bounds__(256) void
k_gatherz(const int* __restrict__ offs, const unsigned short* __restrict__ csr,
          const float* __restrict__ dinv, const float* __restrict__ z,
          const float* __restrict__ consts,
          float* __restrict__ node_out, float* __restrict__ p, float* __restrict__ q,
          int N) {
  int wave = (int)((blockIdx.x * (size_t)blockDim.x + threadIdx.x) >> 6);
  int lane = threadIdx.x & 63;
  if (wave >= N) return;
  int group = lane >> 1;     // 32 edge-groups
  int sub   = lane & 1;      // which float4 half of the row
  float dv = dinv[wave];
  int j0 = offs[wave], j1 = offs[wave + 1];

  float4 acc = make_float4(0.0f, 0.0f, 0.0f, 0.0f);
  if (group == 0) {
    float4 v = *(const float4*)(z + (size_t)wave * 8 + sub * 4);
    float sc = dv * dv;
    acc = make_float4(v.x * sc, v.y * sc, v.z * sc, v.w * sc);
  }

  for (int base = j0; base < j1; base += 64) {
    int myj = base + lane;
    int s_l = 0; float dv_l = 0.0f;
    if (myj < j1) { s_l = (int)csr[myj]; dv_l = dinv[s_l]; }
    int cnt = min(64, j1 - base);
    for (int k = 0; k < cnt; k += 32) {
      int idx = k + group;
      int   s = __shfl(s_l, idx);
      float c = __shfl(dv_l, idx) * dv;
      float4 v = *(const float4*)(z + (size_t)s * 8 + sub * 4);
      acc.x = fmaf(v.x, c, acc.x);
      acc.y = fmaf(v.y, c, acc.y);
      acc.z = fmaf(v.z, c, acc.z);
      acc.w = fmaf(v.w, c, acc.w);
    }
  }

#pragma unroll
  for (int off = 2; off < 64; off <<= 1) {
    acc.x += __shfl_xor(acc.x, off);
    acc.y += __shfl_xor(acc.y, off);
    acc.z += __shfl_xor(acc.z, off);
    acc.w += __shfl_xor(acc.w, off);
  }

  if (lane == 0) {            // channels 0..3: node_x(2), p(2)
    float2 no = make_float2(acc.x + consts[0], acc.y + consts[1]);
    float2 pp = make_float2(acc.z + consts[2], acc.w + consts[3]);
    *(float2*)(node_out + (size_t)wave * 2) = no;
    *(float2*)(p + (size_t)wave * 2) = pp;
  } else if (lane == 1) {     // channels 4..7: q(2)
    float2 qq = make_float2(acc.x + consts[4], acc.y + consts[5]);
    *(float2*)(q + (size_t)wave * 2) = qq;
  }
}

// ---------------- edge output ----------------
__global__ void k_edge(const int* __restrict__ src, const int* __restrict__ dst,
                       const float* __restrict__ p, const float* __restrict__ q,
                       const float* __restrict__ eb, float* __restrict__ eout, int E) {
  int e = blockIdx.x * blockDim.x + threadIdx.x;
  if (e < E) {
    int s = src[e], d = dst[e];
    float2 P = *reinterpret_cast<const float2*>(p + (size_t)s * 2);
    float2 Q = *reinterpret_cast<const float2*>(q + (size_t)d * 2);
    float2 o;
    o.x = P.x + Q.x + eb[0];
    o.y = P.y + Q.y + eb[1];
    *reinterpret_cast<float2*>(eout + (size_t)e * 2) = o;
  }
}

extern "C" void kernel_launch(void* const* d_in, const int* in_sizes, int n_in,
                              void* d_out, int out_size, void* d_ws, size_t ws_size,
                              hipStream_t stream) {
  const float* x   = (const float*)d_in[0];
  const int*   ei  = (const int*)d_in[1];
  const float* W1  = (const float*)d_in[2];
  const float* b1  = (const float*)d_in[3];
  const float* W2  = (const float*)d_in[4];
  const float* b2  = (const float*)d_in[5];
  const float* nW  = (const float*)d_in[6];
  const float* nb  = (const float*)d_in[7];
  const float* eW  = (const float*)d_in[8];
  const float* eb  = (const float*)d_in[9];

  const int N = in_sizes[0] / DIN;   // 50000
  const int E = in_sizes[1] / 2;     // 800000
  const int* src = ei;
  const int* dst = ei + E;

  // ---- workspace layout ----
  float* fws   = (float*)d_ws;
  float* dinv  = fws;                            // N
  float* p     = dinv + N;                       // 2N
  float* q     = p + 2 * (size_t)N;              // 2N
  float* z     = q + 2 * (size_t)N;              // 8N
  float* Wzp   = z + 8 * (size_t)N;              // 4096 (padded [256,16])
  float* consts = Wzp + 4096;                    // 8
  _Float16* xh    = (_Float16*)(consts + 8);     // 64N
  _Float16* aggxh = xh + (size_t)DIN * N;        // 64N
  _Float16* h     = aggxh + (size_t)DIN * N;     // 256N
  _Float16* Wf1   = h + (size_t)H1 * N;          // DIN*H1 = 16384
  _Float16* Wzf   = Wf1 + DIN * H1;              // 256*16 = 4096
  int* hist = (int*)(Wzf + 4096);                // N
  int* offs = hist + N;                          // N+1
  int* bsum = offs + N + 1;                      // 64 (pad to keep alignment)
  unsigned short* rank = (unsigned short*)(bsum + 64);   // E
  unsigned short* csr  = rank + E;                        // E

  float* node_out = (float*)d_out;                   // 2N
  float* edge_out = (float*)d_out + 2 * (size_t)N;   // 2E

  const int nb_blk = (N + 1023) / 1024;

  // ---- CSR build ----
  k_zero<<<(N + 255) / 256, 256, 0, stream>>>(hist, N);
  k_hist<<<(E + 255) / 256, 256, 0, stream>>>(dst, hist, rank, E);
  k_dinv<<<(N + 255) / 256, 256, 0, stream>>>(hist, dinv, N);
  k_scan1<<<nb_blk, 256, 0, stream>>>(hist, offs, bsum, N);
  k_scan2<<<1, 64, 0, stream>>>(bsum, offs, nb_blk, N, E);
  k_scan3<<<nb_blk, 256, 0, stream>>>(offs, bsum, N);
  k_build<<<(E + 255) / 256, 256, 0, stream>>>(src, dst, rank, offs, csr, E);

  // ---- weight prep + x cast ----
  k_wfrag<DIN, H1><<<(DIN * H1 + 255) / 256, 256, 0, stream>>>(W1, Wf1);
  k_wz<<<1, 256, 0, stream>>>(W2, nW, nb, eW, b2, Wzp, consts);
  k_wfrag<H1, 16><<<(H1 * 16 + 255) / 256, 256, 0, stream>>>(Wzp, Wzf);
  k_cast<<<((N * DIN / 8) + 255) / 256, 256, 0, stream>>>(x, xh, N * DIN / 8);

  // ---- layer 1: aggregate-then-transform ----
  k_gather<DIN, false><<<(N + 3) / 4, 256, 0, stream>>>(offs, csr, dinv, xh, nullptr, aggxh, N);
  k_mgemm<DIN, H1, true, true><<<(N + 127) / 128, 256, 0, stream>>>(aggxh, Wf1, b1, h, N);

  // ---- fused layer-2 + heads: z = h@Wz via MFMA, aggregate 6-dim z ----
  k_mgemmz<<<(N + 127) / 128, 256, 0, stream>>>(h, Wzf, z, N);
  k_gatherz<<<(N + 3) / 4, 256, 0, stream>>>(offs, csr, dinv, z, consts, node_out, p, q, N);

  // ---- edge output ----
  k_edge<<<(E + 255) / 256, 256, 0, stream>>>(src, dst, p, q, eb, edge_out, E);
}

// Round 9
// 166.794 us; speedup vs baseline: 1.4080x; 1.1010x over previous
//
#include <hip/hip_runtime.h>

static constexpr int DIN = 64;
static constexpr int H1  = 256;
static constexpr int H2  = 128;

using half8 = _Float16 __attribute__((ext_vector_type(8)));
using f32x4 = float __attribute__((ext_vector_type(4)));

// ---------------- fused prep: zero hist | cast x->fp16 | W1 frag | Wz fused-frag ----------------
// block ranges: [0,NB0): zero hist ; [NB0,NB1): cast ; [NB1,NB2): wfrag1 ; NB2: wz
__global__ __launch_bounds__(256) void
k_prep(int* __restrict__ hist, int N,
       const float* __restrict__ x, _Float16* __restrict__ xh, int nvec8,
       const float* __restrict__ W1, _Float16* __restrict__ Wf1,
       const float* __restrict__ W2, const float* __restrict__ nW,
       const float* __restrict__ nb, const float* __restrict__ eW,
       const float* __restrict__ b2, _Float16* __restrict__ Wzf,
       float* __restrict__ consts,
       int NB0, int NB1, int NB2) {
  const int b = blockIdx.x;
  const int t = threadIdx.x;
  if (b < NB0) {
    int i = b * 256 + t;
    if (i < N) hist[i] = 0;
  } else if (b < NB1) {
    int i = (b - NB0) * 256 + t;
    if (i < nvec8) {
      const float4* x4 = (const float4*)x;
      float4 a = x4[i * 2 + 0];
      float4 bb = x4[i * 2 + 1];
      half8 h;
      h[0] = (_Float16)a.x; h[1] = (_Float16)a.y; h[2] = (_Float16)a.z; h[3] = (_Float16)a.w;
      h[4] = (_Float16)bb.x; h[5] = (_Float16)bb.y; h[6] = (_Float16)bb.z; h[7] = (_Float16)bb.w;
      *(half8*)(xh + (size_t)i * 8) = h;
    }
  } else if (b < NB2) {
    // W1[DIN][H1] -> fragment order (K=DIN, NOUT=H1)
    int i = (b - NB1) * 256 + t;
    if (i < DIN * H1) {
      int j    = i & 7;
      int lane = (i >> 3) & 63;
      int rest = i >> 9;
      int tt   = rest % (DIN / 32);
      int c    = rest / (DIN / 32);
      int k    = tt * 32 + (lane >> 4) * 8 + j;
      int col  = c * 16 + (lane & 15);
      Wf1[i] = (_Float16)W1[k * H1 + col];
    }
  } else {
    // Wz fused-head weights, written directly in fragment order (K=256, NOUT=16)
    int k = t;   // 0..255
    float acc[6] = {0, 0, 0, 0, 0, 0};
    for (int m = 0; m < H2; ++m) {
      float w = W2[k * H2 + m];
      acc[0] = fmaf(w, nW[m * 2 + 0], acc[0]);
      acc[1] = fmaf(w, nW[m * 2 + 1], acc[1]);
      acc[2] = fmaf(w, eW[m * 2 + 0], acc[2]);
      acc[3] = fmaf(w, eW[m * 2 + 1], acc[3]);
      acc[4] = fmaf(w, eW[(H2 + m) * 2 + 0], acc[4]);
      acc[5] = fmaf(w, eW[(H2 + m) * 2 + 1], acc[5]);
    }
    int tt = k >> 5, rem = k & 31, kb = rem >> 3, j = rem & 7;
#pragma unroll
    for (int col = 0; col < 16; ++col) {
      int lane = kb * 16 + col;
      int i = ((size_t)(tt * 64 + lane)) * 8 + j;
      Wzf[i] = (_Float16)((col < 6) ? acc[col] : 0.0f);
    }
    if (k == 0) {
      float c0 = nb[0], c1 = nb[1], c2 = 0, c3 = 0, c4 = 0, c5 = 0;
      for (int m = 0; m < H2; ++m) {
        float bv = b2[m];
        c0 = fmaf(bv, nW[m * 2 + 0], c0);
        c1 = fmaf(bv, nW[m * 2 + 1], c1);
        c2 = fmaf(bv, eW[m * 2 + 0], c2);
        c3 = fmaf(bv, eW[m * 2 + 1], c3);
        c4 = fmaf(bv, eW[(H2 + m) * 2 + 0], c4);
        c5 = fmaf(bv, eW[(H2 + m) * 2 + 1], c5);
      }
      consts[0] = c0; consts[1] = c1; consts[2] = c2;
      consts[3] = c3; consts[4] = c4; consts[5] = c5;
      consts[6] = 0.0f; consts[7] = 0.0f;
    }
  }
}

// ---------------- degree histogram + per-edge rank ----------------
__global__ void k_hist(const int* __restrict__ dst, int* __restrict__ hist,
                       unsigned short* __restrict__ rank, int E) {
  int e = blockIdx.x * blockDim.x + threadIdx.x;
  if (e < E) {
    int old = atomicAdd(&hist[dst[e]], 1);
    rank[e] = (unsigned short)old;
  }
}

// ---------------- scan phase 1 (+ fused dinv) ----------------
__global__ void k_scan1(const int* __restrict__ hist, int* __restrict__ offs,
                        int* __restrict__ bsum, float* __restrict__ dinv, int N) {
  __shared__ int ws[4];
  const int t = threadIdx.x;
  const int base = blockIdx.x * 1024 + t * 4;
  int4 v = make_int4(0, 0, 0, 0);
  if (base + 3 < N) v = *(const int4*)(hist + base);
  else {
    if (base + 0 < N) v.x = hist[base + 0];
    if (base + 1 < N) v.y = hist[base + 1];
    if (base + 2 < N) v.z = hist[base + 2];
    if (base + 3 < N) v.w = hist[base + 3];
  }
  if (base + 3 < N) {
    float4 dv = make_float4(rsqrtf((float)v.x + 1.0f), rsqrtf((float)v.y + 1.0f),
                            rsqrtf((float)v.z + 1.0f), rsqrtf((float)v.w + 1.0f));
    *(float4*)(dinv + base) = dv;
  } else {
    if (base + 0 < N) dinv[base + 0] = rsqrtf((float)v.x + 1.0f);
    if (base + 1 < N) dinv[base + 1] = rsqrtf((float)v.y + 1.0f);
    if (base + 2 < N) dinv[base + 2] = rsqrtf((float)v.z + 1.0f);
    if (base + 3 < N) dinv[base + 3] = rsqrtf((float)v.w + 1.0f);
  }
  int tsum = v.x + v.y + v.z + v.w;
  int lane = t & 63, wid = t >> 6;
  int incl = tsum;
#pragma unroll
  for (int off = 1; off < 64; off <<= 1) {
    int u = __shfl_up(incl, off);
    if (lane >= off) incl += u;
  }
  if (lane == 63) ws[wid] = incl;
  __syncthreads();
  int wbase = 0;
  for (int w = 0; w < wid; ++w) wbase += ws[w];
  int excl = wbase + incl - tsum;
  int4 o;
  o.x = excl;
  o.y = excl + v.x;
  o.z = excl + v.x + v.y;
  o.w = excl + v.x + v.y + v.z;
  if (base + 3 < N) *(int4*)(offs + base) = o;
  else {
    if (base + 0 < N) offs[base + 0] = o.x;
    if (base + 1 < N) offs[base + 1] = o.y;
    if (base + 2 < N) offs[base + 2] = o.z;
    if (base + 3 < N) offs[base + 3] = o.w;
  }
  if (t == 255) bsum[blockIdx.x] = wbase + incl;
}

__global__ void k_scan2(int* __restrict__ bsum, int* __restrict__ offs,
                        int nb, int N, int E) {
  int t = threadIdx.x;
  int v = (t < nb) ? bsum[t] : 0;
  int incl = v;
#pragma unroll
  for (int off = 1; off < 64; off <<= 1) {
    int u = __shfl_up(incl, off);
    if (t >= off) incl += u;
  }
  if (t < nb) bsum[t] = incl - v;
  if (t == 0) offs[N] = E;
}

__global__ void k_scan3(int* __restrict__ offs, const int* __restrict__ bsum, int N) {
  if (blockIdx.x == 0) return;
  int b = bsum[blockIdx.x];
  int base = blockIdx.x * 1024 + threadIdx.x * 4;
  if (base + 3 < N) {
    int4 v = *(int4*)(offs + base);
    v.x += b; v.y += b; v.z += b; v.w += b;
    *(int4*)(offs + base) = v;
  } else {
    for (int k = 0; k < 4; ++k) if (base + k < N) offs[base + k] += b;
  }
}

// ---------------- atomic-free CSR build (u16 payload) ----------------
__global__ void k_build(const int* __restrict__ src, const int* __restrict__ dst,
                        const unsigned short* __restrict__ rank,
                        const int* __restrict__ offs,
                        unsigned short* __restrict__ csr, int E) {
  int e = blockIdx.x * blockDim.x + threadIdx.x;
  if (e < E) {
    int d = dst[e];
    int pos = offs[d] + (int)rank[e];
    __builtin_nontemporal_store((unsigned short)src[e], &csr[pos]);
  }
}

// ---------------- MFMA GEMM: C[M,NOUT] = A[M,K] @ W[K,NOUT], fused bias+relu ----------------
template<int K, int NOUT, bool BIAS, bool RELU>
__global__ __launch_bounds__(256) void
k_mgemm(const _Float16* __restrict__ A, const _Float16* __restrict__ Wf,
        const float* __restrict__ bias, _Float16* __restrict__ C, int M) {
  constexpr int NC = NOUT / 16;
  constexpr int NT = K / 32;
  const int wave = threadIdx.x >> 6;
  const int lane = threadIdx.x & 63;
  const int rowbase = blockIdx.x * 128 + wave * 32;
  if (rowbase >= M) return;
  const int r  = lane & 15;
  const int kb = lane >> 4;
  int row0 = rowbase + r;       if (row0 >= M) row0 = M - 1;
  int row1 = rowbase + 16 + r;  if (row1 >= M) row1 = M - 1;
  const _Float16* a0p = A + (size_t)row0 * K + kb * 8;
  const _Float16* a1p = A + (size_t)row1 * K + kb * 8;

  f32x4 acc[2][NC];
#pragma unroll
  for (int rb = 0; rb < 2; ++rb)
#pragma unroll
    for (int c = 0; c < NC; ++c) acc[rb][c] = (f32x4)0.0f;

#pragma unroll
  for (int t = 0; t < NT; ++t) {
    half8 a0 = *(const half8*)(a0p + t * 32);
    half8 a1 = *(const half8*)(a1p + t * 32);
#pragma unroll
    for (int c = 0; c < NC; ++c) {
      half8 bf = ((const half8*)Wf)[(size_t)(c * NT + t) * 64 + lane];
      acc[0][c] = __builtin_amdgcn_mfma_f32_16x16x32_f16(a0, bf, acc[0][c], 0, 0, 0);
      acc[1][c] = __builtin_amdgcn_mfma_f32_16x16x32_f16(a1, bf, acc[1][c], 0, 0, 0);
    }
  }

#pragma unroll
  for (int rb = 0; rb < 2; ++rb) {
    int growbase = rowbase + rb * 16 + kb * 4;
#pragma unroll
    for (int c = 0; c < NC; ++c) {
      int col = c * 16 + r;
      float bv = BIAS ? bias[col] : 0.0f;
#pragma unroll
      for (int j = 0; j < 4; ++j) {
        int grow = growbase + j;
        if (grow < M) {
          float v = acc[rb][c][j] + bv;
          if (RELU) v = fmaxf(v, 0.0f);
          C[(size_t)grow * NOUT + col] = (_Float16)v;
        }
      }
    }
  }
}

// ---------------- MFMA z-GEMM: z[M,8] = h[M,256] @ Wzf[256,16] (cols 0..7 stored) ----------------
__global__ __launch_bounds__(256) void
k_mgemmz(const _Float16* __restrict__ A, const _Float16* __restrict__ Wf,
         float* __restrict__ z, int M) {
  constexpr int K = H1, NT = K / 32;
  const int wave = threadIdx.x >> 6;
  const int lane = threadIdx.x & 63;
  const int rowbase = blockIdx.x * 128 + wave * 32;
  if (rowbase >= M) return;
  const int r  = lane & 15;
  const int kb = lane >> 4;
  int row0 = rowbase + r;       if (row0 >= M) row0 = M - 1;
  int row1 = rowbase + 16 + r;  if (row1 >= M) row1 = M - 1;
  const _Float16* a0p = A + (size_t)row0 * K + kb * 8;
  const _Float16* a1p = A + (size_t)row1 * K + kb * 8;

  f32x4 acc0 = (f32x4)0.0f, acc1 = (f32x4)0.0f;
#pragma unroll
  for (int t = 0; t < NT; ++t) {
    half8 a0 = *(const half8*)(a0p + t * 32);
    half8 a1 = *(const half8*)(a1p + t * 32);
    half8 bf = ((const half8*)Wf)[(size_t)t * 64 + lane];
    acc0 = __builtin_amdgcn_mfma_f32_16x16x32_f16(a0, bf, acc0, 0, 0, 0);
    acc1 = __builtin_amdgcn_mfma_f32_16x16x32_f16(a1, bf, acc1, 0, 0, 0);
  }

  if (r < 8) {
#pragma unroll
    for (int j = 0; j < 4; ++j) {
      int g0 = rowbase + kb * 4 + j;
      if (g0 < M) z[(size_t)g0 * 8 + r] = acc0[j];
      int g1 = rowbase + 16 + kb * 4 + j;
      if (g1 < M) z[(size_t)g1 * 8 + r] = acc1[j];
    }
  }
}

// ---------------- CSR gather (fp16 payload, fp32 accumulate) ----------------
template<int C, bool BIAS>
__global__ __launch_bounds__(256) void
k_gather(const int* __restrict__ offs, const unsigned short* __restrict__ csr,
         const float* __restrict__ dinv, const _Float16* __restrict__ xw,
         const float* __restrict__ bias, _Float16* __restrict__ out, int N) {
  constexpr int GSIZE = C / 8;
  constexpr int NE    = 64 / GSIZE;
  int wave = (int)((blockIdx.x * (size_t)blockDim.x + threadIdx.x) >> 6);
  int lane = threadIdx.x & 63;
  if (wave >= N) return;
  int group = lane / GSIZE;
  int sub   = lane % GSIZE;
  int ch0   = sub * 8;
  float dv = dinv[wave];
  int j0 = offs[wave], j1 = offs[wave + 1];

  float acc[8];
  if (group == 0) {
    half8 v = *(const half8*)(xw + (size_t)wave * C + ch0);
    float sc = dv * dv;
#pragma unroll
    for (int k = 0; k < 8; ++k) acc[k] = (float)v[k] * sc;
  } else {
#pragma unroll
    for (int k = 0; k < 8; ++k) acc[k] = 0.0f;
  }

  for (int base = j0; base < j1; base += 64) {
    int myj = base + lane;
    int s_l = 0; float dv_l = 0.0f;
    if (myj < j1) { s_l = (int)csr[myj]; dv_l = dinv[s_l]; }
    int cnt = min(64, j1 - base);
    for (int k = 0; k < cnt; k += NE) {
      int idx = k + group;
      int   s = __shfl(s_l, idx);
      float c = __shfl(dv_l, idx) * dv;
      if (c != 0.0f) {
        half8 v = *(const half8*)(xw + (size_t)s * C + ch0);
#pragma unroll
        for (int k2 = 0; k2 < 8; ++k2) acc[k2] = fmaf((float)v[k2], c, acc[k2]);
      }
    }
  }

#pragma unroll
  for (int off = GSIZE; off < 64; off <<= 1) {
#pragma unroll
    for (int k = 0; k < 8; ++k) acc[k] += __shfl_xor(acc[k], off);
  }

  if (group == 0) {
    half8 o;
#pragma unroll
    for (int k = 0; k < 8; ++k) {
      float v = acc[k] + (BIAS ? bias[ch0 + k] : 0.0f);
      o[k] = (_Float16)v;
    }
    *(half8*)(out + (size_t)wave * C + ch0) = o;
  }
}

// ---------------- aggregate z (C=8 fp32): 2 nodes per wave -> node_out, p, q ----------------
__global__ __launch_bounds__(256) void
k_gatherz(const int* __restrict__ offs, const unsigned short* __restrict__ csr,
          const float* __restrict__ dinv, const float* __restrict__ z,
          const float* __restrict__ consts,
          float* __restrict__ node_out, float* __restrict__ p, float* __restrict__ q,
          int N) {
  int wave = (int)((blockIdx.x * (size_t)blockDim.x + threadIdx.x) >> 6);
  int lane = threadIdx.x & 63;
  int half = lane >> 5;
  int node = wave * 2 + half;
  if (node >= N) return;
  int lane32 = lane & 31;
  int group  = lane32 >> 1;     // 16 edge-groups per node
  int sub    = lane32 & 1;      // float4 half of the z row
  int hb     = half << 5;       // shfl base for this node's half-wave
  float dv = dinv[node];
  int j0 = offs[node], j1 = offs[node + 1];

  float4 acc = make_float4(0.0f, 0.0f, 0.0f, 0.0f);
  if (group == 0) {
    float4 v = *(const float4*)(z + (size_t)node * 8 + sub * 4);
    float sc = dv * dv;
    acc = make_float4(v.x * sc, v.y * sc, v.z * sc, v.w * sc);
  }

  for (int base = j0; base < j1; base += 32) {
    int myj = base + lane32;
    int s_l = 0; float dv_l = 0.0f;
    if (myj < j1) { s_l = (int)csr[myj]; dv_l = dinv[s_l]; }
    int cnt = min(32, j1 - base);
    for (int k = 0; k < cnt; k += 16) {
      int idx = k + group;
      int   s = __shfl(s_l, hb + idx);
      float c = __shfl(dv_l, hb + idx) * dv;
      if (c != 0.0f) {
        float4 v = *(const float4*)(z + (size_t)s * 8 + sub * 4);
        acc.x = fmaf(v.x, c, acc.x);
        acc.y = fmaf(v.y, c, acc.y);
        acc.z = fmaf(v.z, c, acc.z);
        acc.w = fmaf(v.w, c, acc.w);
      }
    }
  }

#pragma unroll
  for (int off = 2; off < 32; off <<= 1) {
    acc.x += __shfl_xor(acc.x, off);
    acc.y += __shfl_xor(acc.y, off);
    acc.z += __shfl_xor(acc.z, off);
    acc.w += __shfl_xor(acc.w, off);
  }

  if (lane32 == 0) {            // channels 0..3: node_x(2), p(2)
    float2 no = make_float2(acc.x + consts[0], acc.y + consts[1]);
    float2 pp = make_float2(acc.z + consts[2], acc.w + consts[3]);
    *(float2*)(node_out + (size_t)node * 2) = no;
    *(float2*)(p + (size_t)node * 2) = pp;
  } else if (lane32 == 1) {     // channels 4..7: q(2)
    float2 qq = make_float2(acc.x + consts[4], acc.y + consts[5]);
    *(float2*)(q + (size_t)node * 2) = qq;
  }
}

// ---------------- edge output: 2 edges per thread ----------------
__global__ void k_edge(const int* __restrict__ src, const int* __restrict__ dst,
                       const float* __restrict__ p, const float* __restrict__ q,
                       const float* __restrict__ eb, float* __restrict__ eout, int E) {
  int i = blockIdx.x * blockDim.x + threadIdx.x;
  int e = i * 2;
  float e0 = eb[0], e1 = eb[1];
  if (e + 1 < E) {
    int2 s2 = *(const int2*)(src + e);
    int2 d2 = *(const int2*)(dst + e);
    float2 P0 = *(const float2*)(p + (size_t)s2.x * 2);
    float2 Q0 = *(const float2*)(q + (size_t)d2.x * 2);
    float2 P1 = *(const float2*)(p + (size_t)s2.y * 2);
    float2 Q1 = *(const float2*)(q + (size_t)d2.y * 2);
    float4 o;
    o.x = P0.x + Q0.x + e0;
    o.y = P0.y + Q0.y + e1;
    o.z = P1.x + Q1.x + e0;
    o.w = P1.y + Q1.y + e1;
    *(float4*)(eout + (size_t)e * 2) = o;
  } else if (e < E) {
    int s = src[e], d = dst[e];
    float2 P = *(const float2*)(p + (size_t)s * 2);
    float2 Q = *(const float2*)(q + (size_t)d * 2);
    float2 o;
    o.x = P.x + Q.x + e0;
    o.y = P.y + Q.y + e1;
    *(float2*)(eout + (size_t)e * 2) = o;
  }
}

extern "C" void kernel_launch(void* const* d_in, const int* in_sizes, int n_in,
                              void* d_out, int out_size, void* d_ws, size_t ws_size,
                              hipStream_t stream) {
  const float* x   = (const float*)d_in[0];
  const int*   ei  = (const int*)d_in[1];
  const float* W1  = (const float*)d_in[2];
  const float* b1  = (const float*)d_in[3];
  const float* W2  = (const float*)d_in[4];
  const float* b2  = (const float*)d_in[5];
  const float* nW  = (const float*)d_in[6];
  const float* nb  = (const float*)d_in[7];
  const float* eW  = (const float*)d_in[8];
  const float* eb  = (const float*)d_in[9];

  const int N = in_sizes[0] / DIN;   // 50000
  const int E = in_sizes[1] / 2;     // 800000
  const int* src = ei;
  const int* dst = ei + E;

  // ---- workspace layout ----
  float* fws   = (float*)d_ws;
  float* dinv  = fws;                            // N
  float* p     = dinv + N;                       // 2N
  float* q     = p + 2 * (size_t)N;              // 2N
  float* z     = q + 2 * (size_t)N;              // 8N
  float* consts = z + 8 * (size_t)N;             // 8
  _Float16* xh    = (_Float16*)(consts + 8);     // 64N
  _Float16* aggxh = xh + (size_t)DIN * N;        // 64N
  _Float16* h     = aggxh + (size_t)DIN * N;     // 256N
  _Float16* Wf1   = h + (size_t)H1 * N;          // DIN*H1 = 16384
  _Float16* Wzf   = Wf1 + DIN * H1;              // 256*16 = 4096
  int* hist = (int*)(Wzf + 4096);                // N
  int* offs = hist + N;                          // N+1
  int* bsum = offs + N + 1;                      // 64
  unsigned short* rank = (unsigned short*)(bsum + 64);   // E
  unsigned short* csr  = rank + E;                        // E

  float* node_out = (float*)d_out;                   // 2N
  float* edge_out = (float*)d_out + 2 * (size_t)N;   // 2E

  const int nb_blk = (N + 1023) / 1024;
  const int nvec8  = N * DIN / 8;

  // prep grid composition
  const int NB0 = (N + 255) / 256;               // zero hist
  const int NB1 = NB0 + (nvec8 + 255) / 256;     // cast
  const int NB2 = NB1 + (DIN * H1 + 255) / 256;  // wfrag1
  const int NBP = NB2 + 1;                       // + wz block

  // ---- prep (zero | cast | wfrag1 | wz) + CSR build ----
  k_prep<<<NBP, 256, 0, stream>>>(hist, N, x, xh, nvec8, W1, Wf1,
                                  W2, nW, nb, eW, b2, Wzf, consts, NB0, NB1, NB2);
  k_hist<<<(E + 255) / 256, 256, 0, stream>>>(dst, hist, rank, E);
  k_scan1<<<nb_blk, 256, 0, stream>>>(hist, offs, bsum, dinv, N);
  k_scan2<<<1, 64, 0, stream>>>(bsum, offs, nb_blk, N, E);
  k_scan3<<<nb_blk, 256, 0, stream>>>(offs, bsum, N);
  k_build<<<(E + 255) / 256, 256, 0, stream>>>(src, dst, rank, offs, csr, E);

  // ---- layer 1: aggregate-then-transform ----
  k_gather<DIN, false><<<(N + 3) / 4, 256, 0, stream>>>(offs, csr, dinv, xh, nullptr, aggxh, N);
  k_mgemm<DIN, H1, true, true><<<(N + 127) / 128, 256, 0, stream>>>(aggxh, Wf1, b1, h, N);

  // ---- fused layer-2 + heads ----
  k_mgemmz<<<(N + 127) / 128, 256, 0, stream>>>(h, Wzf, z, N);
  k_gatherz<<<((N + 1) / 2 + 3) / 4, 256, 0, stream>>>(offs, csr, dinv, z, consts, node_out, p, q, N);

  // ---- edge output ----
  k_edge<<<((E + 1) / 2 + 255) / 256, 256, 0, stream>>>(src, dst, p, q, eb, edge_out, E);
}

// Round 10
// 148.289 us; speedup vs baseline: 1.5837x; 1.1248x over previous
//
#include <hip/hip_runtime.h>

static constexpr int DIN = 64;
static constexpr int H1  = 256;
static constexpr int H2  = 128;

using half8 = _Float16 __attribute__((ext_vector_type(8)));
using f32x4 = float __attribute__((ext_vector_type(4)));

// ---------------- fused prep: zero hist | cast x->fp16 | W1 frag | Wz8 fused-head ----------------
// block ranges: [0,NB0): zero hist ; [NB0,NB1): cast ; [NB1,NB2): wfrag1 ; NB2: wz
__global__ __launch_bounds__(256) void
k_prep(int* __restrict__ hist, int N,
       const float* __restrict__ x, _Float16* __restrict__ xh, int nvec8,
       const float* __restrict__ W1, _Float16* __restrict__ Wf1,
       const float* __restrict__ W2, const float* __restrict__ nW,
       const float* __restrict__ nb, const float* __restrict__ eW,
       const float* __restrict__ b2, float* __restrict__ Wz8,
       float* __restrict__ consts,
       int NB0, int NB1, int NB2) {
  const int b = blockIdx.x;
  const int t = threadIdx.x;
  if (b < NB0) {
    int i = b * 256 + t;
    if (i < N) hist[i] = 0;
  } else if (b < NB1) {
    int i = (b - NB0) * 256 + t;
    if (i < nvec8) {
      const float4* x4 = (const float4*)x;
      float4 a = x4[i * 2 + 0];
      float4 bb = x4[i * 2 + 1];
      half8 h;
      h[0] = (_Float16)a.x; h[1] = (_Float16)a.y; h[2] = (_Float16)a.z; h[3] = (_Float16)a.w;
      h[4] = (_Float16)bb.x; h[5] = (_Float16)bb.y; h[6] = (_Float16)bb.z; h[7] = (_Float16)bb.w;
      *(half8*)(xh + (size_t)i * 8) = h;
    }
  } else if (b < NB2) {
    // W1[DIN][H1] -> fragment order (K=DIN, NOUT=H1)
    int i = (b - NB1) * 256 + t;
    if (i < DIN * H1) {
      int j    = i & 7;
      int lane = (i >> 3) & 63;
      int rest = i >> 9;
      int tt   = rest % (DIN / 32);
      int c    = rest / (DIN / 32);
      int k    = tt * 32 + (lane >> 4) * 8 + j;
      int col  = c * 16 + (lane & 15);
      Wf1[i] = (_Float16)W1[k * H1 + col];
    }
  } else {
    // Wz8[k][8] = (W2 @ [nW|eWtop|eWbot])[k], fp32, channels 6..7 zero
    int k = t;   // 0..255
    float acc[6] = {0, 0, 0, 0, 0, 0};
    for (int m = 0; m < H2; ++m) {
      float w = W2[k * H2 + m];
      acc[0] = fmaf(w, nW[m * 2 + 0], acc[0]);
      acc[1] = fmaf(w, nW[m * 2 + 1], acc[1]);
      acc[2] = fmaf(w, eW[m * 2 + 0], acc[2]);
      acc[3] = fmaf(w, eW[m * 2 + 1], acc[3]);
      acc[4] = fmaf(w, eW[(H2 + m) * 2 + 0], acc[4]);
      acc[5] = fmaf(w, eW[(H2 + m) * 2 + 1], acc[5]);
    }
#pragma unroll
    for (int c = 0; c < 6; ++c) Wz8[k * 8 + c] = acc[c];
    Wz8[k * 8 + 6] = 0.0f; Wz8[k * 8 + 7] = 0.0f;
    if (k == 0) {
      float c0 = nb[0], c1 = nb[1], c2 = 0, c3 = 0, c4 = 0, c5 = 0;
      for (int m = 0; m < H2; ++m) {
        float bv = b2[m];
        c0 = fmaf(bv, nW[m * 2 + 0], c0);
        c1 = fmaf(bv, nW[m * 2 + 1], c1);
        c2 = fmaf(bv, eW[m * 2 + 0], c2);
        c3 = fmaf(bv, eW[m * 2 + 1], c3);
        c4 = fmaf(bv, eW[(H2 + m) * 2 + 0], c4);
        c5 = fmaf(bv, eW[(H2 + m) * 2 + 1], c5);
      }
      consts[0] = c0; consts[1] = c1; consts[2] = c2;
      consts[3] = c3; consts[4] = c4; consts[5] = c5;
      consts[6] = 0.0f; consts[7] = 0.0f;
    }
  }
}

// ---------------- degree histogram + per-edge rank ----------------
__global__ void k_hist(const int* __restrict__ dst, int* __restrict__ hist,
                       unsigned short* __restrict__ rank, int E) {
  int e = blockIdx.x * blockDim.x + threadIdx.x;
  if (e < E) {
    int old = atomicAdd(&hist[dst[e]], 1);
    rank[e] = (unsigned short)old;
  }
}

// ---------------- scan phase 1 (+ fused dinv) ----------------
__global__ void k_scan1(const int* __restrict__ hist, int* __restrict__ offs,
                        int* __restrict__ bsum, float* __restrict__ dinv, int N) {
  __shared__ int ws[4];
  const int t = threadIdx.x;
  const int base = blockIdx.x * 1024 + t * 4;
  int4 v = make_int4(0, 0, 0, 0);
  if (base + 3 < N) v = *(const int4*)(hist + base);
  else {
    if (base + 0 < N) v.x = hist[base + 0];
    if (base + 1 < N) v.y = hist[base + 1];
    if (base + 2 < N) v.z = hist[base + 2];
    if (base + 3 < N) v.w = hist[base + 3];
  }
  if (base + 3 < N) {
    float4 dv = make_float4(rsqrtf((float)v.x + 1.0f), rsqrtf((float)v.y + 1.0f),
                            rsqrtf((float)v.z + 1.0f), rsqrtf((float)v.w + 1.0f));
    *(float4*)(dinv + base) = dv;
  } else {
    if (base + 0 < N) dinv[base + 0] = rsqrtf((float)v.x + 1.0f);
    if (base + 1 < N) dinv[base + 1] = rsqrtf((float)v.y + 1.0f);
    if (base + 2 < N) dinv[base + 2] = rsqrtf((float)v.z + 1.0f);
    if (base + 3 < N) dinv[base + 3] = rsqrtf((float)v.w + 1.0f);
  }
  int tsum = v.x + v.y + v.z + v.w;
  int lane = t & 63, wid = t >> 6;
  int incl = tsum;
#pragma unroll
  for (int off = 1; off < 64; off <<= 1) {
    int u = __shfl_up(incl, off);
    if (lane >= off) incl += u;
  }
  if (lane == 63) ws[wid] = incl;
  __syncthreads();
  int wbase = 0;
  for (int w = 0; w < wid; ++w) wbase += ws[w];
  int excl = wbase + incl - tsum;
  int4 o;
  o.x = excl;
  o.y = excl + v.x;
  o.z = excl + v.x + v.y;
  o.w = excl + v.x + v.y + v.z;
  if (base + 3 < N) *(int4*)(offs + base) = o;
  else {
    if (base + 0 < N) offs[base + 0] = o.x;
    if (base + 1 < N) offs[base + 1] = o.y;
    if (base + 2 < N) offs[base + 2] = o.z;
    if (base + 3 < N) offs[base + 3] = o.w;
  }
  if (t == 255) bsum[blockIdx.x] = wbase + incl;
}

// ---------------- scan phase 2+3 fused: every block re-scans bsum, adds base ----------------
__global__ void k_scan3(int* __restrict__ offs, const int* __restrict__ bsum,
                        int nb, int N, int E) {
  __shared__ int sbase;
  const int t = threadIdx.x;
  if (t < 64) {
    int v = (t < nb) ? bsum[t] : 0;
    int incl = v;
#pragma unroll
    for (int off = 1; off < 64; off <<= 1) {
      int u = __shfl_up(incl, off);
      if (t >= off) incl += u;
    }
    if (t == (int)blockIdx.x) sbase = incl - v;   // exclusive prefix for this block
  }
  __syncthreads();
  int b = sbase;
  if (blockIdx.x == 0 && t == 0) offs[N] = E;
  if (b == 0) return;
  int base = blockIdx.x * 1024 + t * 4;
  if (base + 3 < N) {
    int4 v = *(int4*)(offs + base);
    v.x += b; v.y += b; v.z += b; v.w += b;
    *(int4*)(offs + base) = v;
  } else {
    for (int k = 0; k < 4; ++k) if (base + k < N) offs[base + k] += b;
  }
}

// ---------------- atomic-free CSR build (u16 payload) ----------------
__global__ void k_build(const int* __restrict__ src, const int* __restrict__ dst,
                        const unsigned short* __restrict__ rank,
                        const int* __restrict__ offs,
                        unsigned short* __restrict__ csr, int E) {
  int e = blockIdx.x * blockDim.x + threadIdx.x;
  if (e < E) {
    int d = dst[e];
    int pos = offs[d] + (int)rank[e];
    __builtin_nontemporal_store((unsigned short)src[e], &csr[pos]);
  }
}

// ---------------- CSR gather (fp16 payload, fp32 accumulate) ----------------
template<int C, bool BIAS>
__global__ __launch_bounds__(256) void
k_gather(const int* __restrict__ offs, const unsigned short* __restrict__ csr,
         const float* __restrict__ dinv, const _Float16* __restrict__ xw,
         const float* __restrict__ bias, _Float16* __restrict__ out, int N) {
  constexpr int GSIZE = C / 8;
  constexpr int NE    = 64 / GSIZE;
  int wave = (int)((blockIdx.x * (size_t)blockDim.x + threadIdx.x) >> 6);
  int lane = threadIdx.x & 63;
  if (wave >= N) return;
  int group = lane / GSIZE;
  int sub   = lane % GSIZE;
  int ch0   = sub * 8;
  float dv = dinv[wave];
  int j0 = offs[wave], j1 = offs[wave + 1];

  float acc[8];
  if (group == 0) {
    half8 v = *(const half8*)(xw + (size_t)wave * C + ch0);
    float sc = dv * dv;
#pragma unroll
    for (int k = 0; k < 8; ++k) acc[k] = (float)v[k] * sc;
  } else {
#pragma unroll
    for (int k = 0; k < 8; ++k) acc[k] = 0.0f;
  }

  for (int base = j0; base < j1; base += 64) {
    int myj = base + lane;
    int s_l = 0; float dv_l = 0.0f;
    if (myj < j1) { s_l = (int)csr[myj]; dv_l = dinv[s_l]; }
    int cnt = min(64, j1 - base);
    for (int k = 0; k < cnt; k += NE) {
      int idx = k + group;
      int   s = __shfl(s_l, idx);
      float c = __shfl(dv_l, idx) * dv;
      if (c != 0.0f) {
        half8 v = *(const half8*)(xw + (size_t)s * C + ch0);
#pragma unroll
        for (int k2 = 0; k2 < 8; ++k2) acc[k2] = fmaf((float)v[k2], c, acc[k2]);
      }
    }
  }

#pragma unroll
  for (int off = GSIZE; off < 64; off <<= 1) {
#pragma unroll
    for (int k = 0; k < 8; ++k) acc[k] += __shfl_xor(acc[k], off);
  }

  if (group == 0) {
    half8 o;
#pragma unroll
    for (int k = 0; k < 8; ++k) {
      float v = acc[k] + (BIAS ? bias[ch0 + k] : 0.0f);
      o[k] = (_Float16)v;
    }
    *(half8*)(out + (size_t)wave * C + ch0) = o;
  }
}

// ---------------- fused MFMA GEMM + head projection:
//   h_rows = relu(aggx @ W1 + b1) held in registers, z = h_rows @ Wz8 written directly ----------------
__global__ __launch_bounds__(256) void
k_mgemm_z(const _Float16* __restrict__ A, const _Float16* __restrict__ Wf,
          const float* __restrict__ bias, const float* __restrict__ Wz8,
          float* __restrict__ z, int M) {
  constexpr int K = DIN, NOUT = H1;
  constexpr int NC = NOUT / 16;   // 16
  constexpr int NT = K / 32;      // 2
  const int wave = threadIdx.x >> 6;
  const int lane = threadIdx.x & 63;
  const int rowbase = blockIdx.x * 128 + wave * 32;
  if (rowbase >= M) return;
  const int r  = lane & 15;
  const int kb = lane >> 4;
  int row0 = rowbase + r;       if (row0 >= M) row0 = M - 1;
  int row1 = rowbase + 16 + r;  if (row1 >= M) row1 = M - 1;
  const _Float16* a0p = A + (size_t)row0 * K + kb * 8;
  const _Float16* a1p = A + (size_t)row1 * K + kb * 8;

  f32x4 acc[2][NC];
#pragma unroll
  for (int rb = 0; rb < 2; ++rb)
#pragma unroll
    for (int c = 0; c < NC; ++c) acc[rb][c] = (f32x4)0.0f;

#pragma unroll
  for (int t = 0; t < NT; ++t) {
    half8 a0 = *(const half8*)(a0p + t * 32);
    half8 a1 = *(const half8*)(a1p + t * 32);
#pragma unroll
    for (int c = 0; c < NC; ++c) {
      half8 bf = ((const half8*)Wf)[(size_t)(c * NT + t) * 64 + lane];
      acc[0][c] = __builtin_amdgcn_mfma_f32_16x16x32_f16(a0, bf, acc[0][c], 0, 0, 0);
      acc[1][c] = __builtin_amdgcn_mfma_f32_16x16x32_f16(a1, bf, acc[1][c], 0, 0, 0);
    }
  }

  // epilogue: hv = relu(acc + b1[col]); zc[rb][j][ch] += hv * Wz8[col][ch]
  // lane holds cols {c*16 + r : c in 0..15} for rows growbase..growbase+3 (x2 rb)
  float zc[2][4][6];
#pragma unroll
  for (int rb = 0; rb < 2; ++rb)
#pragma unroll
    for (int j = 0; j < 4; ++j)
#pragma unroll
      for (int ch = 0; ch < 6; ++ch) zc[rb][j][ch] = 0.0f;

#pragma unroll
  for (int c = 0; c < NC; ++c) {
    int col = c * 16 + r;
    const float* wp = Wz8 + col * 8;
    float4 w0 = *(const float4*)wp;
    float2 w1 = *(const float2*)(wp + 4);
    float bv = bias[col];
#pragma unroll
    for (int rb = 0; rb < 2; ++rb) {
#pragma unroll
      for (int j = 0; j < 4; ++j) {
        float hv = fmaxf(acc[rb][c][j] + bv, 0.0f);
        zc[rb][j][0] = fmaf(hv, w0.x, zc[rb][j][0]);
        zc[rb][j][1] = fmaf(hv, w0.y, zc[rb][j][1]);
        zc[rb][j][2] = fmaf(hv, w0.z, zc[rb][j][2]);
        zc[rb][j][3] = fmaf(hv, w0.w, zc[rb][j][3]);
        zc[rb][j][4] = fmaf(hv, w1.x, zc[rb][j][4]);
        zc[rb][j][5] = fmaf(hv, w1.y, zc[rb][j][5]);
      }
    }
  }

  // reduce over the 16 lanes (r) sharing each row
#pragma unroll
  for (int off = 1; off < 16; off <<= 1) {
#pragma unroll
    for (int rb = 0; rb < 2; ++rb)
#pragma unroll
      for (int j = 0; j < 4; ++j)
#pragma unroll
        for (int ch = 0; ch < 6; ++ch)
          zc[rb][j][ch] += __shfl_xor(zc[rb][j][ch], off);
  }

  if (r == 0) {
#pragma unroll
    for (int rb = 0; rb < 2; ++rb) {
      int growbase = rowbase + rb * 16 + kb * 4;
#pragma unroll
      for (int j = 0; j < 4; ++j) {
        int grow = growbase + j;
        if (grow < M) {
          float4 lo = make_float4(zc[rb][j][0], zc[rb][j][1], zc[rb][j][2], zc[rb][j][3]);
          float4 hi = make_float4(zc[rb][j][4], zc[rb][j][5], 0.0f, 0.0f);
          *(float4*)(z + (size_t)grow * 8)     = lo;
          *(float4*)(z + (size_t)grow * 8 + 4) = hi;
        }
      }
    }
  }
}

// ---------------- aggregate z (C=8 fp32): 2 nodes per wave -> node_out, p, q ----------------
__global__ __launch_bounds__(256) void
k_gatherz(const int* __restrict__ offs, const unsigned short* __restrict__ csr,
          const float* __restrict__ dinv, const float* __restrict__ z,
          const float* __restrict__ consts,
          float* __restrict__ node_out, float* __restrict__ p, float* __restrict__ q,
          int N) {
  int wave = (int)((blockIdx.x * (size_t)blockDim.x + threadIdx.x) >> 6);
  int lane = threadIdx.x & 63;
  int half = lane >> 5;
  int node = wave * 2 + half;
  if (node >= N) return;
  int lane32 = lane & 31;
  int group  = lane32 >> 1;     // 16 edge-groups per node
  int sub    = lane32 & 1;      // float4 half of the z row
  int hb     = half << 5;       // shfl base for this node's half-wave
  float dv = dinv[node];
  int j0 = offs[node], j1 = offs[node + 1];

  float4 acc = make_float4(0.0f, 0.0f, 0.0f, 0.0f);
  if (group == 0) {
    float4 v = *(const float4*)(z + (size_t)node * 8 + sub * 4);
    float sc = dv * dv;
    acc = make_float4(v.x * sc, v.y * sc, v.z * sc, v.w * sc);
  }

  for (int base = j0; base < j1; base += 32) {
    int myj = base + lane32;
    int s_l = 0; float dv_l = 0.0f;
    if (myj < j1) { s_l = (int)csr[myj]; dv_l = dinv[s_l]; }
    int cnt = min(32, j1 - base);
    for (int k = 0; k < cnt; k += 16) {
      int idx = k + group;
      int   s = __shfl(s_l, hb + idx);
      float c = __shfl(dv_l, hb + idx) * dv;
      if (c != 0.0f) {
        float4 v = *(const float4*)(z + (size_t)s * 8 + sub * 4);
        acc.x = fmaf(v.x, c, acc.x);
        acc.y = fmaf(v.y, c, acc.y);
        acc.z = fmaf(v.z, c, acc.z);
        acc.w = fmaf(v.w, c, acc.w);
      }
    }
  }

#pragma unroll
  for (int off = 2; off < 32; off <<= 1) {
    acc.x += __shfl_xor(acc.x, off);
    acc.y += __shfl_xor(acc.y, off);
    acc.z += __shfl_xor(acc.z, off);
    acc.w += __shfl_xor(acc.w, off);
  }

  if (lane32 == 0) {            // channels 0..3: node_x(2), p(2)
    float2 no = make_float2(acc.x + consts[0], acc.y + consts[1]);
    float2 pp = make_float2(acc.z + consts[2], acc.w + consts[3]);
    *(float2*)(node_out + (size_t)node * 2) = no;
    *(float2*)(p + (size_t)node * 2) = pp;
  } else if (lane32 == 1) {     // channels 4..7: q(2)
    float2 qq = make_float2(acc.x + consts[4], acc.y + consts[5]);
    *(float2*)(q + (size_t)node * 2) = qq;
  }
}

// ---------------- edge output: 2 edges per thread ----------------
__global__ void k_edge(const int* __restrict__ src, const int* __restrict__ dst,
                       const float* __restrict__ p, const float* __restrict__ q,
                       const float* __restrict__ eb, float* __restrict__ eout, int E) {
  int i = blockIdx.x * blockDim.x + threadIdx.x;
  int e = i * 2;
  float e0 = eb[0], e1 = eb[1];
  if (e + 1 < E) {
    int2 s2 = *(const int2*)(src + e);
    int2 d2 = *(const int2*)(dst + e);
    float2 P0 = *(const float2*)(p + (size_t)s2.x * 2);
    float2 Q0 = *(const float2*)(q + (size_t)d2.x * 2);
    float2 P1 = *(const float2*)(p + (size_t)s2.y * 2);
    float2 Q1 = *(const float2*)(q + (size_t)d2.y * 2);
    float4 o;
    o.x = P0.x + Q0.x + e0;
    o.y = P0.y + Q0.y + e1;
    o.z = P1.x + Q1.x + e0;
    o.w = P1.y + Q1.y + e1;
    *(float4*)(eout + (size_t)e * 2) = o;
  } else if (e < E) {
    int s = src[e], d = dst[e];
    float2 P = *(const float2*)(p + (size_t)s * 2);
    float2 Q = *(const float2*)(q + (size_t)d * 2);
    float2 o;
    o.x = P.x + Q.x + e0;
    o.y = P.y + Q.y + e1;
    *(float2*)(eout + (size_t)e * 2) = o;
  }
}

extern "C" void kernel_launch(void* const* d_in, const int* in_sizes, int n_in,
                              void* d_out, int out_size, void* d_ws, size_t ws_size,
                              hipStream_t stream) {
  const float* x   = (const float*)d_in[0];
  const int*   ei  = (const int*)d_in[1];
  const float* W1  = (const float*)d_in[2];
  const float* b1  = (const float*)d_in[3];
  const float* W2  = (const float*)d_in[4];
  const float* b2  = (const float*)d_in[5];
  const float* nW  = (const float*)d_in[6];
  const float* nb  = (const float*)d_in[7];
  const float* eW  = (const float*)d_in[8];
  const float* eb  = (const float*)d_in[9];

  const int N = in_sizes[0] / DIN;   // 50000
  const int E = in_sizes[1] / 2;     // 800000
  const int* src = ei;
  const int* dst = ei + E;

  // ---- workspace layout ----
  float* fws   = (float*)d_ws;
  float* dinv  = fws;                            // N
  float* p     = dinv + N;                       // 2N
  float* q     = p + 2 * (size_t)N;              // 2N
  float* z     = q + 2 * (size_t)N;              // 8N
  float* Wz8   = z + 8 * (size_t)N;              // 2048
  float* consts = Wz8 + 2048;                    // 8
  _Float16* xh    = (_Float16*)(consts + 8);     // 64N
  _Float16* aggxh = xh + (size_t)DIN * N;        // 64N
  _Float16* Wf1   = aggxh + (size_t)DIN * N;     // DIN*H1 = 16384
  int* hist = (int*)(Wf1 + DIN * H1);            // N
  int* offs = hist + N;                          // N+1
  int* bsum = offs + N + 1;                      // 64
  unsigned short* rank = (unsigned short*)(bsum + 64);   // E
  unsigned short* csr  = rank + E;                        // E

  float* node_out = (float*)d_out;                   // 2N
  float* edge_out = (float*)d_out + 2 * (size_t)N;   // 2E

  const int nb_blk = (N + 1023) / 1024;
  const int nvec8  = N * DIN / 8;

  // prep grid composition
  const int NB0 = (N + 255) / 256;               // zero hist
  const int NB1 = NB0 + (nvec8 + 255) / 256;     // cast
  const int NB2 = NB1 + (DIN * H1 + 255) / 256;  // wfrag1
  const int NBP = NB2 + 1;                       // + wz block

  // ---- prep (zero | cast | wfrag1 | wz) + CSR build ----
  k_prep<<<NBP, 256, 0, stream>>>(hist, N, x, xh, nvec8, W1, Wf1,
                                  W2, nW, nb, eW, b2, Wz8, consts, NB0, NB1, NB2);
  k_hist<<<(E + 255) / 256, 256, 0, stream>>>(dst, hist, rank, E);
  k_scan1<<<nb_blk, 256, 0, stream>>>(hist, offs, bsum, dinv, N);
  k_scan3<<<nb_blk, 256, 0, stream>>>(offs, bsum, nb_blk, N, E);
  k_build<<<(E + 255) / 256, 256, 0, stream>>>(src, dst, rank, offs, csr, E);

  // ---- layer 1 aggregate, then fused transform + head projection ----
  k_gather<DIN, false><<<(N + 3) / 4, 256, 0, stream>>>(offs, csr, dinv, xh, nullptr, aggxh, N);
  k_mgemm_z<<<(N + 127) / 128, 256, 0, stream>>>(aggxh, Wf1, b1, Wz8, z, N);

  // ---- aggregate 6-dim z -> node_out, p, q ----
  k_gatherz<<<((N + 1) / 2 + 3) / 4, 256, 0, stream>>>(offs, csr, dinv, z, consts, node_out, p, q, N);

  // ---- edge output ----
  k_edge<<<((E + 1) / 2 + 255) / 256, 256, 0, stream>>>(src, dst, p, q, eb, edge_out, E);
}

// Round 11
// 144.424 us; speedup vs baseline: 1.6261x; 1.0268x over previous
//
#include <hip/hip_runtime.h>

static constexpr int DIN = 64;
static constexpr int H1  = 256;
static constexpr int H2  = 128;

using half8 = _Float16 __attribute__((ext_vector_type(8)));
using f32x4 = float __attribute__((ext_vector_type(4)));

__device__ __forceinline__ unsigned short f2h_bits(float f) {
  _Float16 h = (_Float16)f;
  unsigned short u;
  __builtin_memcpy(&u, &h, 2);
  return u;
}
__device__ __forceinline__ float h_bits2f(unsigned u) {
  unsigned short us = (unsigned short)(u & 0xffffu);
  _Float16 h;
  __builtin_memcpy(&h, &us, 2);
  return (float)h;
}

// ---------------- fused prep: zero hist | cast x->fp16 | W1 frag | Wz8 fused-head ----------------
__global__ __launch_bounds__(256) void
k_prep(int* __restrict__ hist, int N,
       const float* __restrict__ x, _Float16* __restrict__ xh, int nvec8,
       const float* __restrict__ W1, _Float16* __restrict__ Wf1,
       const float* __restrict__ W2, const float* __restrict__ nW,
       const float* __restrict__ nb, const float* __restrict__ eW,
       const float* __restrict__ b2, float* __restrict__ Wz8,
       float* __restrict__ consts,
       int NB0, int NB1, int NB2) {
  const int b = blockIdx.x;
  const int t = threadIdx.x;
  if (b < NB0) {
    int i = b * 256 + t;
    if (i < N) hist[i] = 0;
  } else if (b < NB1) {
    int i = (b - NB0) * 256 + t;
    if (i < nvec8) {
      const float4* x4 = (const float4*)x;
      float4 a = x4[i * 2 + 0];
      float4 bb = x4[i * 2 + 1];
      half8 h;
      h[0] = (_Float16)a.x; h[1] = (_Float16)a.y; h[2] = (_Float16)a.z; h[3] = (_Float16)a.w;
      h[4] = (_Float16)bb.x; h[5] = (_Float16)bb.y; h[6] = (_Float16)bb.z; h[7] = (_Float16)bb.w;
      *(half8*)(xh + (size_t)i * 8) = h;
    }
  } else if (b < NB2) {
    int i = (b - NB1) * 256 + t;
    if (i < DIN * H1) {
      int j    = i & 7;
      int lane = (i >> 3) & 63;
      int rest = i >> 9;
      int tt   = rest % (DIN / 32);
      int c    = rest / (DIN / 32);
      int k    = tt * 32 + (lane >> 4) * 8 + j;
      int col  = c * 16 + (lane & 15);
      Wf1[i] = (_Float16)W1[k * H1 + col];
    }
  } else {
    int k = t;   // 0..255
    float acc[6] = {0, 0, 0, 0, 0, 0};
    for (int m = 0; m < H2; ++m) {
      float w = W2[k * H2 + m];
      acc[0] = fmaf(w, nW[m * 2 + 0], acc[0]);
      acc[1] = fmaf(w, nW[m * 2 + 1], acc[1]);
      acc[2] = fmaf(w, eW[m * 2 + 0], acc[2]);
      acc[3] = fmaf(w, eW[m * 2 + 1], acc[3]);
      acc[4] = fmaf(w, eW[(H2 + m) * 2 + 0], acc[4]);
      acc[5] = fmaf(w, eW[(H2 + m) * 2 + 1], acc[5]);
    }
#pragma unroll
    for (int c = 0; c < 6; ++c) Wz8[k * 8 + c] = acc[c];
    Wz8[k * 8 + 6] = 0.0f; Wz8[k * 8 + 7] = 0.0f;
    if (k == 0) {
      float c0 = nb[0], c1 = nb[1], c2 = 0, c3 = 0, c4 = 0, c5 = 0;
      for (int m = 0; m < H2; ++m) {
        float bv = b2[m];
        c0 = fmaf(bv, nW[m * 2 + 0], c0);
        c1 = fmaf(bv, nW[m * 2 + 1], c1);
        c2 = fmaf(bv, eW[m * 2 + 0], c2);
        c3 = fmaf(bv, eW[m * 2 + 1], c3);
        c4 = fmaf(bv, eW[(H2 + m) * 2 + 0], c4);
        c5 = fmaf(bv, eW[(H2 + m) * 2 + 1], c5);
      }
      consts[0] = c0; consts[1] = c1; consts[2] = c2;
      consts[3] = c3; consts[4] = c4; consts[5] = c5;
      consts[6] = 0.0f; consts[7] = 0.0f;
    }
  }
}

// ---------------- degree histogram + per-edge rank (2 edges/thread) ----------------
__global__ void k_hist(const int* __restrict__ dst, int* __restrict__ hist,
                       unsigned short* __restrict__ rank, int E) {
  int i = blockIdx.x * blockDim.x + threadIdx.x;
  int e = i * 2;
  if (e + 1 < E) {
    int2 d2 = *(const int2*)(dst + e);
    int r0 = atomicAdd(&hist[d2.x], 1);
    int r1 = atomicAdd(&hist[d2.y], 1);
    unsigned pk = (unsigned)(r0 & 0xffff) | ((unsigned)(r1 & 0xffff) << 16);
    *(unsigned*)(rank + e) = pk;
  } else if (e < E) {
    int r = atomicAdd(&hist[dst[e]], 1);
    rank[e] = (unsigned short)r;
  }
}

// ---------------- scan phase 1 (+ fused dinv) ----------------
__global__ void k_scan1(const int* __restrict__ hist, int* __restrict__ offs,
                        int* __restrict__ bsum, float* __restrict__ dinv, int N) {
  __shared__ int ws[4];
  const int t = threadIdx.x;
  const int base = blockIdx.x * 1024 + t * 4;
  int4 v = make_int4(0, 0, 0, 0);
  if (base + 3 < N) v = *(const int4*)(hist + base);
  else {
    if (base + 0 < N) v.x = hist[base + 0];
    if (base + 1 < N) v.y = hist[base + 1];
    if (base + 2 < N) v.z = hist[base + 2];
    if (base + 3 < N) v.w = hist[base + 3];
  }
  if (base + 3 < N) {
    float4 dv = make_float4(rsqrtf((float)v.x + 1.0f), rsqrtf((float)v.y + 1.0f),
                            rsqrtf((float)v.z + 1.0f), rsqrtf((float)v.w + 1.0f));
    *(float4*)(dinv + base) = dv;
  } else {
    if (base + 0 < N) dinv[base + 0] = rsqrtf((float)v.x + 1.0f);
    if (base + 1 < N) dinv[base + 1] = rsqrtf((float)v.y + 1.0f);
    if (base + 2 < N) dinv[base + 2] = rsqrtf((float)v.z + 1.0f);
    if (base + 3 < N) dinv[base + 3] = rsqrtf((float)v.w + 1.0f);
  }
  int tsum = v.x + v.y + v.z + v.w;
  int lane = t & 63, wid = t >> 6;
  int incl = tsum;
#pragma unroll
  for (int off = 1; off < 64; off <<= 1) {
    int u = __shfl_up(incl, off);
    if (lane >= off) incl += u;
  }
  if (lane == 63) ws[wid] = incl;
  __syncthreads();
  int wbase = 0;
  for (int w = 0; w < wid; ++w) wbase += ws[w];
  int excl = wbase + incl - tsum;
  int4 o;
  o.x = excl;
  o.y = excl + v.x;
  o.z = excl + v.x + v.y;
  o.w = excl + v.x + v.y + v.z;
  if (base + 3 < N) *(int4*)(offs + base) = o;
  else {
    if (base + 0 < N) offs[base + 0] = o.x;
    if (base + 1 < N) offs[base + 1] = o.y;
    if (base + 2 < N) offs[base + 2] = o.z;
    if (base + 3 < N) offs[base + 3] = o.w;
  }
  if (t == 255) bsum[blockIdx.x] = wbase + incl;
}

// ---------------- scan phase 2+3 fused ----------------
__global__ void k_scan3(int* __restrict__ offs, const int* __restrict__ bsum,
                        int nb, int N, int E) {
  __shared__ int sbase;
  const int t = threadIdx.x;
  if (t < 64) {
    int v = (t < nb) ? bsum[t] : 0;
    int incl = v;
#pragma unroll
    for (int off = 1; off < 64; off <<= 1) {
      int u = __shfl_up(incl, off);
      if (t >= off) incl += u;
    }
    if (t == (int)blockIdx.x) sbase = incl - v;
  }
  __syncthreads();
  int b = sbase;
  if (blockIdx.x == 0 && t == 0) offs[N] = E;
  if (b == 0) return;
  int base = blockIdx.x * 1024 + t * 4;
  if (base + 3 < N) {
    int4 v = *(int4*)(offs + base);
    v.x += b; v.y += b; v.z += b; v.w += b;
    *(int4*)(offs + base) = v;
  } else {
    for (int k = 0; k < 4; ++k) if (base + k < N) offs[base + k] += b;
  }
}

// ---------------- CSR build: csr[pos] = (src<<16) | fp16(dinv[src]), 2 edges/thread ----------------
__global__ void k_build(const int* __restrict__ src, const int* __restrict__ dst,
                        const unsigned short* __restrict__ rank,
                        const int* __restrict__ offs, const float* __restrict__ dinv,
                        unsigned* __restrict__ csr, int E) {
  int i = blockIdx.x * blockDim.x + threadIdx.x;
  int e = i * 2;
  if (e + 1 < E) {
    int2 s2 = *(const int2*)(src + e);
    int2 d2 = *(const int2*)(dst + e);
    unsigned rr = *(const unsigned*)(rank + e);
    int pos0 = offs[d2.x] + (int)(rr & 0xffffu);
    int pos1 = offs[d2.y] + (int)(rr >> 16);
    unsigned v0 = ((unsigned)s2.x << 16) | f2h_bits(dinv[s2.x]);
    unsigned v1 = ((unsigned)s2.y << 16) | f2h_bits(dinv[s2.y]);
    __builtin_nontemporal_store(v0, &csr[pos0]);
    __builtin_nontemporal_store(v1, &csr[pos1]);
  } else if (e < E) {
    int s = src[e], d = dst[e];
    int pos = offs[d] + (int)rank[e];
    unsigned v = ((unsigned)s << 16) | f2h_bits(dinv[s]);
    __builtin_nontemporal_store(v, &csr[pos]);
  }
}

// ---------------- CSR gather C=64 (fp16 payload, packed src+coef, fp32 accumulate) ----------------
__global__ __launch_bounds__(256) void
k_gather64(const int* __restrict__ offs, const unsigned* __restrict__ csr,
           const float* __restrict__ dinv, const _Float16* __restrict__ xw,
           _Float16* __restrict__ out, int N) {
  constexpr int C = 64, GSIZE = 8, NE = 8;
  int wave = (int)((blockIdx.x * (size_t)blockDim.x + threadIdx.x) >> 6);
  int lane = threadIdx.x & 63;
  if (wave >= N) return;
  int group = lane / GSIZE;
  int sub   = lane % GSIZE;
  int ch0   = sub * 8;
  float dv = dinv[wave];
  int j0 = offs[wave], j1 = offs[wave + 1];

  float acc[8];
  if (group == 0) {
    half8 v = *(const half8*)(xw + (size_t)wave * C + ch0);
    float sc = dv * dv;
#pragma unroll
    for (int k = 0; k < 8; ++k) acc[k] = (float)v[k] * sc;
  } else {
#pragma unroll
    for (int k = 0; k < 8; ++k) acc[k] = 0.0f;
  }

  for (int base = j0; base < j1; base += 64) {
    int myj = base + lane;
    unsigned u_l = 0;
    if (myj < j1) u_l = csr[myj];
    int cnt = min(64, j1 - base);
    for (int k = 0; k < cnt; k += NE) {
      unsigned u = (unsigned)__shfl((int)u_l, k + group);
      if (u != 0) {
        int   s = (int)(u >> 16);
        float c = h_bits2f(u) * dv;
        half8 v = *(const half8*)(xw + (size_t)s * C + ch0);
#pragma unroll
        for (int k2 = 0; k2 < 8; ++k2) acc[k2] = fmaf((float)v[k2], c, acc[k2]);
      }
    }
  }

#pragma unroll
  for (int off = GSIZE; off < 64; off <<= 1) {
#pragma unroll
    for (int k = 0; k < 8; ++k) acc[k] += __shfl_xor(acc[k], off);
  }

  if (group == 0) {
    half8 o;
#pragma unroll
    for (int k = 0; k < 8; ++k) o[k] = (_Float16)acc[k];
    *(half8*)(out + (size_t)wave * C + ch0) = o;
  }
}

// ---------------- fused MFMA GEMM + head projection ----------------
__global__ __launch_bounds__(256) void
k_mgemm_z(const _Float16* __restrict__ A, const _Float16* __restrict__ Wf,
          const float* __restrict__ bias, const float* __restrict__ Wz8,
          float* __restrict__ z, int M) {
  constexpr int K = DIN, NOUT = H1;
  constexpr int NC = NOUT / 16;   // 16
  constexpr int NT = K / 32;      // 2
  const int wave = threadIdx.x >> 6;
  const int lane = threadIdx.x & 63;
  const int rowbase = blockIdx.x * 128 + wave * 32;
  if (rowbase >= M) return;
  const int r  = lane & 15;
  const int kb = lane >> 4;
  int row0 = rowbase + r;       if (row0 >= M) row0 = M - 1;
  int row1 = rowbase + 16 + r;  if (row1 >= M) row1 = M - 1;
  const _Float16* a0p = A + (size_t)row0 * K + kb * 8;
  const _Float16* a1p = A + (size_t)row1 * K + kb * 8;

  f32x4 acc[2][NC];
#pragma unroll
  for (int rb = 0; rb < 2; ++rb)
#pragma unroll
    for (int c = 0; c < NC; ++c) acc[rb][c] = (f32x4)0.0f;

#pragma unroll
  for (int t = 0; t < NT; ++t) {
    half8 a0 = *(const half8*)(a0p + t * 32);
    half8 a1 = *(const half8*)(a1p + t * 32);
#pragma unroll
    for (int c = 0; c < NC; ++c) {
      half8 bf = ((const half8*)Wf)[(size_t)(c * NT + t) * 64 + lane];
      acc[0][c] = __builtin_amdgcn_mfma_f32_16x16x32_f16(a0, bf, acc[0][c], 0, 0, 0);
      acc[1][c] = __builtin_amdgcn_mfma_f32_16x16x32_f16(a1, bf, acc[1][c], 0, 0, 0);
    }
  }

  float zc[2][4][6];
#pragma unroll
  for (int rb = 0; rb < 2; ++rb)
#pragma unroll
    for (int j = 0; j < 4; ++j)
#pragma unroll
      for (int ch = 0; ch < 6; ++ch) zc[rb][j][ch] = 0.0f;

#pragma unroll
  for (int c = 0; c < NC; ++c) {
    int col = c * 16 + r;
    const float* wp = Wz8 + col * 8;
    float4 w0 = *(const float4*)wp;
    float2 w1 = *(const float2*)(wp + 4);
    float bv = bias[col];
#pragma unroll
    for (int rb = 0; rb < 2; ++rb) {
#pragma unroll
      for (int j = 0; j < 4; ++j) {
        float hv = fmaxf(acc[rb][c][j] + bv, 0.0f);
        zc[rb][j][0] = fmaf(hv, w0.x, zc[rb][j][0]);
        zc[rb][j][1] = fmaf(hv, w0.y, zc[rb][j][1]);
        zc[rb][j][2] = fmaf(hv, w0.z, zc[rb][j][2]);
        zc[rb][j][3] = fmaf(hv, w0.w, zc[rb][j][3]);
        zc[rb][j][4] = fmaf(hv, w1.x, zc[rb][j][4]);
        zc[rb][j][5] = fmaf(hv, w1.y, zc[rb][j][5]);
      }
    }
  }

#pragma unroll
  for (int off = 1; off < 16; off <<= 1) {
#pragma unroll
    for (int rb = 0; rb < 2; ++rb)
#pragma unroll
      for (int j = 0; j < 4; ++j)
#pragma unroll
        for (int ch = 0; ch < 6; ++ch)
          zc[rb][j][ch] += __shfl_xor(zc[rb][j][ch], off);
  }

  if (r == 0) {
#pragma unroll
    for (int rb = 0; rb < 2; ++rb) {
      int growbase = rowbase + rb * 16 + kb * 4;
#pragma unroll
      for (int j = 0; j < 4; ++j) {
        int grow = growbase + j;
        if (grow < M) {
          float4 lo = make_float4(zc[rb][j][0], zc[rb][j][1], zc[rb][j][2], zc[rb][j][3]);
          float4 hi = make_float4(zc[rb][j][4], zc[rb][j][5], 0.0f, 0.0f);
          *(float4*)(z + (size_t)grow * 8)     = lo;
          *(float4*)(z + (size_t)grow * 8 + 4) = hi;
        }
      }
    }
  }
}

// ---------------- aggregate z (C=8 fp32): 4 nodes per wave -> node_out, p, q ----------------
__global__ __launch_bounds__(256) void
k_gatherz(const int* __restrict__ offs, const unsigned* __restrict__ csr,
          const float* __restrict__ dinv, const float* __restrict__ z,
          const float* __restrict__ consts,
          float* __restrict__ node_out, float* __restrict__ p, float* __restrict__ q,
          int N) {
  int wave = (int)((blockIdx.x * (size_t)blockDim.x + threadIdx.x) >> 6);
  int lane = threadIdx.x & 63;
  int quad = lane >> 4;           // 0..3
  int node = wave * 4 + quad;
  if (node >= N) return;
  int l16   = lane & 15;
  int group = l16 >> 1;           // 8 edge-groups per node
  int sub   = l16 & 1;            // float4 half of the z row
  int hb    = quad << 4;          // shfl base for this node's 16-lane quad
  float dv = dinv[node];
  int j0 = offs[node], j1 = offs[node + 1];

  float4 acc = make_float4(0.0f, 0.0f, 0.0f, 0.0f);
  if (group == 0) {
    float4 v = *(const float4*)(z + (size_t)node * 8 + sub * 4);
    float sc = dv * dv;
    acc = make_float4(v.x * sc, v.y * sc, v.z * sc, v.w * sc);
  }

  for (int base = j0; base < j1; base += 16) {
    int myj = base + l16;
    unsigned u_l = 0;
    if (myj < j1) u_l = csr[myj];
    int cnt = min(16, j1 - base);
    for (int k = 0; k < cnt; k += 8) {
      unsigned u = (unsigned)__shfl((int)u_l, hb + k + group);
      if (u != 0) {
        int   s = (int)(u >> 16);
        float c = h_bits2f(u) * dv;
        float4 v = *(const float4*)(z + (size_t)s * 8 + sub * 4);
        acc.x = fmaf(v.x, c, acc.x);
        acc.y = fmaf(v.y, c, acc.y);
        acc.z = fmaf(v.z, c, acc.z);
        acc.w = fmaf(v.w, c, acc.w);
      }
    }
  }

#pragma unroll
  for (int off = 2; off < 16; off <<= 1) {
    acc.x += __shfl_xor(acc.x, off);
    acc.y += __shfl_xor(acc.y, off);
    acc.z += __shfl_xor(acc.z, off);
    acc.w += __shfl_xor(acc.w, off);
  }

  if (l16 == 0) {               // channels 0..3: node_x(2), p(2)
    float2 no = make_float2(acc.x + consts[0], acc.y + consts[1]);
    float2 pp = make_float2(acc.z + consts[2], acc.w + consts[3]);
    *(float2*)(node_out + (size_t)node * 2) = no;
    *(float2*)(p + (size_t)node * 2) = pp;
  } else if (l16 == 1) {        // channels 4..7: q(2)
    float2 qq = make_float2(acc.x + consts[4], acc.y + consts[5]);
    *(float2*)(q + (size_t)node * 2) = qq;
  }
}

// ---------------- edge output: 2 edges per thread ----------------
__global__ void k_edge(const int* __restrict__ src, const int* __restrict__ dst,
                       const float* __restrict__ p, const float* __restrict__ q,
                       const float* __restrict__ eb, float* __restrict__ eout, int E) {
  int i = blockIdx.x * blockDim.x + threadIdx.x;
  int e = i * 2;
  float e0 = eb[0], e1 = eb[1];
  if (e + 1 < E) {
    int2 s2 = *(const int2*)(src + e);
    int2 d2 = *(const int2*)(dst + e);
    float2 P0 = *(const float2*)(p + (size_t)s2.x * 2);
    float2 Q0 = *(const float2*)(q + (size_t)d2.x * 2);
    float2 P1 = *(const float2*)(p + (size_t)s2.y * 2);
    float2 Q1 = *(const float2*)(q + (size_t)d2.y * 2);
    float4 o;
    o.x = P0.x + Q0.x + e0;
    o.y = P0.y + Q0.y + e1;
    o.z = P1.x + Q1.x + e0;
    o.w = P1.y + Q1.y + e1;
    *(float4*)(eout + (size_t)e * 2) = o;
  } else if (e < E) {
    int s = src[e], d = dst[e];
    float2 P = *(const float2*)(p + (size_t)s * 2);
    float2 Q = *(const float2*)(q + (size_t)d * 2);
    float2 o;
    o.x = P.x + Q.x + e0;
    o.y = P.y + Q.y + e1;
    *(float2*)(eout + (size_t)e * 2) = o;
  }
}

extern "C" void kernel_launch(void* const* d_in, const int* in_sizes, int n_in,
                              void* d_out, int out_size, void* d_ws, size_t ws_size,
                              hipStream_t stream) {
  const float* x   = (const float*)d_in[0];
  const int*   ei  = (const int*)d_in[1];
  const float* W1  = (const float*)d_in[2];
  const float* b1  = (const float*)d_in[3];
  const float* W2  = (const float*)d_in[4];
  const float* b2  = (const float*)d_in[5];
  const float* nW  = (const float*)d_in[6];
  const float* nb  = (const float*)d_in[7];
  const float* eW  = (const float*)d_in[8];
  const float* eb  = (const float*)d_in[9];

  const int N = in_sizes[0] / DIN;   // 50000
  const int E = in_sizes[1] / 2;     // 800000
  const int* src = ei;
  const int* dst = ei + E;

  // ---- workspace layout ----
  float* fws   = (float*)d_ws;
  float* dinv  = fws;                            // N
  float* p     = dinv + N;                       // 2N
  float* q     = p + 2 * (size_t)N;              // 2N
  float* z     = q + 2 * (size_t)N;              // 8N
  float* Wz8   = z + 8 * (size_t)N;              // 2048
  float* consts = Wz8 + 2048;                    // 8
  _Float16* xh    = (_Float16*)(consts + 8);     // 64N
  _Float16* aggxh = xh + (size_t)DIN * N;        // 64N
  _Float16* Wf1   = aggxh + (size_t)DIN * N;     // DIN*H1 = 16384
  int* hist = (int*)(Wf1 + DIN * H1);            // N
  int* offs = hist + N;                          // N+1
  int* bsum = offs + N + 1;                      // 64
  unsigned short* rank = (unsigned short*)(bsum + 64);   // E (u16)
  unsigned* csr = (unsigned*)(rank + E);                  // E (u32 packed src|fp16 dinv)

  float* node_out = (float*)d_out;                   // 2N
  float* edge_out = (float*)d_out + 2 * (size_t)N;   // 2E

  const int nb_blk = (N + 1023) / 1024;
  const int nvec8  = N * DIN / 8;

  const int NB0 = (N + 255) / 256;
  const int NB1 = NB0 + (nvec8 + 255) / 256;
  const int NB2 = NB1 + (DIN * H1 + 255) / 256;
  const int NBP = NB2 + 1;

  // ---- prep + CSR build ----
  k_prep<<<NBP, 256, 0, stream>>>(hist, N, x, xh, nvec8, W1, Wf1,
                                  W2, nW, nb, eW, b2, Wz8, consts, NB0, NB1, NB2);
  k_hist<<<((E + 1) / 2 + 255) / 256, 256, 0, stream>>>(dst, hist, rank, E);
  k_scan1<<<nb_blk, 256, 0, stream>>>(hist, offs, bsum, dinv, N);
  k_scan3<<<nb_blk, 256, 0, stream>>>(offs, bsum, nb_blk, N, E);
  k_build<<<((E + 1) / 2 + 255) / 256, 256, 0, stream>>>(src, dst, rank, offs, dinv, csr, E);

  // ---- layer 1 aggregate, then fused transform + head projection ----
  k_gather64<<<(N + 3) / 4, 256, 0, stream>>>(offs, csr, dinv, xh, aggxh, N);
  k_mgemm_z<<<(N + 127) / 128, 256, 0, stream>>>(aggxh, Wf1, b1, Wz8, z, N);

  // ---- aggregate 6-dim z -> node_out, p, q ----
  {
    int waves = (N + 3) / 4;
    k_gatherz<<<(waves + 3) / 4, 256, 0, stream>>>(offs, csr, dinv, z, consts, node_out, p, q, N);
  }

  // ---- edge output ----
  k_edge<<<((E + 1) / 2 + 255) / 256, 256, 0, stream>>>(src, dst, p, q, eb, edge_out, E);
}

// Round 12
// 141.218 us; speedup vs baseline: 1.6630x; 1.0227x over previous
//
#include <hip/hip_runtime.h>

static constexpr int DIN = 64;
static constexpr int H1  = 256;
static constexpr int H2  = 128;

using half8 = _Float16 __attribute__((ext_vector_type(8)));
using f32x4 = float __attribute__((ext_vector_type(4)));

__device__ __forceinline__ unsigned short f2h_bits(float f) {
  _Float16 h = (_Float16)f;
  unsigned short u;
  __builtin_memcpy(&u, &h, 2);
  return u;
}
__device__ __forceinline__ float h_bits2f(unsigned u) {
  unsigned short us = (unsigned short)(u & 0xffffu);
  _Float16 h;
  __builtin_memcpy(&h, &us, 2);
  return (float)h;
}

// ---------------- fused prep: zero hist | cast x->fp16 | W1 frag | Wz8 fused-head ----------------
__global__ __launch_bounds__(256) void
k_prep(int* __restrict__ hist, int N,
       const float* __restrict__ x, _Float16* __restrict__ xh, int nvec8,
       const float* __restrict__ W1, _Float16* __restrict__ Wf1,
       const float* __restrict__ W2, const float* __restrict__ nW,
       const float* __restrict__ nb, const float* __restrict__ eW,
       const float* __restrict__ b2, float* __restrict__ Wz8,
       float* __restrict__ consts,
       int NB0, int NB1, int NB2) {
  const int b = blockIdx.x;
  const int t = threadIdx.x;
  if (b < NB0) {
    int i = b * 256 + t;
    if (i < N) hist[i] = 0;
  } else if (b < NB1) {
    int i = (b - NB0) * 256 + t;
    if (i < nvec8) {
      const float4* x4 = (const float4*)x;
      float4 a = x4[i * 2 + 0];
      float4 bb = x4[i * 2 + 1];
      half8 h;
      h[0] = (_Float16)a.x; h[1] = (_Float16)a.y; h[2] = (_Float16)a.z; h[3] = (_Float16)a.w;
      h[4] = (_Float16)bb.x; h[5] = (_Float16)bb.y; h[6] = (_Float16)bb.z; h[7] = (_Float16)bb.w;
      *(half8*)(xh + (size_t)i * 8) = h;
    }
  } else if (b < NB2) {
    int i = (b - NB1) * 256 + t;
    if (i < DIN * H1) {
      int j    = i & 7;
      int lane = (i >> 3) & 63;
      int rest = i >> 9;
      int tt   = rest % (DIN / 32);
      int c    = rest / (DIN / 32);
      int k    = tt * 32 + (lane >> 4) * 8 + j;
      int col  = c * 16 + (lane & 15);
      Wf1[i] = (_Float16)W1[k * H1 + col];
    }
  } else {
    int k = t;   // 0..255
    float acc[6] = {0, 0, 0, 0, 0, 0};
    for (int m = 0; m < H2; ++m) {
      float w = W2[k * H2 + m];
      acc[0] = fmaf(w, nW[m * 2 + 0], acc[0]);
      acc[1] = fmaf(w, nW[m * 2 + 1], acc[1]);
      acc[2] = fmaf(w, eW[m * 2 + 0], acc[2]);
      acc[3] = fmaf(w, eW[m * 2 + 1], acc[3]);
      acc[4] = fmaf(w, eW[(H2 + m) * 2 + 0], acc[4]);
      acc[5] = fmaf(w, eW[(H2 + m) * 2 + 1], acc[5]);
    }
#pragma unroll
    for (int c = 0; c < 6; ++c) Wz8[k * 8 + c] = acc[c];
    Wz8[k * 8 + 6] = 0.0f; Wz8[k * 8 + 7] = 0.0f;
    if (k == 0) {
      float c0 = nb[0], c1 = nb[1], c2 = 0, c3 = 0, c4 = 0, c5 = 0;
      for (int m = 0; m < H2; ++m) {
        float bv = b2[m];
        c0 = fmaf(bv, nW[m * 2 + 0], c0);
        c1 = fmaf(bv, nW[m * 2 + 1], c1);
        c2 = fmaf(bv, eW[m * 2 + 0], c2);
        c3 = fmaf(bv, eW[m * 2 + 1], c3);
        c4 = fmaf(bv, eW[(H2 + m) * 2 + 0], c4);
        c5 = fmaf(bv, eW[(H2 + m) * 2 + 1], c5);
      }
      consts[0] = c0; consts[1] = c1; consts[2] = c2;
      consts[3] = c3; consts[4] = c4; consts[5] = c5;
      consts[6] = 0.0f; consts[7] = 0.0f;
    }
  }
}

// ---------------- degree histogram + per-edge rank (2 edges/thread) ----------------
__global__ void k_hist(const int* __restrict__ dst, int* __restrict__ hist,
                       unsigned short* __restrict__ rank, int E) {
  int i = blockIdx.x * blockDim.x + threadIdx.x;
  int e = i * 2;
  if (e + 1 < E) {
    int2 d2 = *(const int2*)(dst + e);
    int r0 = atomicAdd(&hist[d2.x], 1);
    int r1 = atomicAdd(&hist[d2.y], 1);
    unsigned pk = (unsigned)(r0 & 0xffff) | ((unsigned)(r1 & 0xffff) << 16);
    *(unsigned*)(rank + e) = pk;
  } else if (e < E) {
    int r = atomicAdd(&hist[dst[e]], 1);
    rank[e] = (unsigned short)r;
  }
}

// ---------------- scan phase 1 (+ fused dinv); offs stays BLOCK-LOCAL ----------------
__global__ void k_scan1(const int* __restrict__ hist, int* __restrict__ offs,
                        int* __restrict__ bsum, float* __restrict__ dinv, int N) {
  __shared__ int ws[4];
  const int t = threadIdx.x;
  const int base = blockIdx.x * 1024 + t * 4;
  int4 v = make_int4(0, 0, 0, 0);
  if (base + 3 < N) v = *(const int4*)(hist + base);
  else {
    if (base + 0 < N) v.x = hist[base + 0];
    if (base + 1 < N) v.y = hist[base + 1];
    if (base + 2 < N) v.z = hist[base + 2];
    if (base + 3 < N) v.w = hist[base + 3];
  }
  if (base + 3 < N) {
    float4 dv = make_float4(rsqrtf((float)v.x + 1.0f), rsqrtf((float)v.y + 1.0f),
                            rsqrtf((float)v.z + 1.0f), rsqrtf((float)v.w + 1.0f));
    *(float4*)(dinv + base) = dv;
  } else {
    if (base + 0 < N) dinv[base + 0] = rsqrtf((float)v.x + 1.0f);
    if (base + 1 < N) dinv[base + 1] = rsqrtf((float)v.y + 1.0f);
    if (base + 2 < N) dinv[base + 2] = rsqrtf((float)v.z + 1.0f);
    if (base + 3 < N) dinv[base + 3] = rsqrtf((float)v.w + 1.0f);
  }
  int tsum = v.x + v.y + v.z + v.w;
  int lane = t & 63, wid = t >> 6;
  int incl = tsum;
#pragma unroll
  for (int off = 1; off < 64; off <<= 1) {
    int u = __shfl_up(incl, off);
    if (lane >= off) incl += u;
  }
  if (lane == 63) ws[wid] = incl;
  __syncthreads();
  int wbase = 0;
  for (int w = 0; w < wid; ++w) wbase += ws[w];
  int excl = wbase + incl - tsum;
  int4 o;
  o.x = excl;
  o.y = excl + v.x;
  o.z = excl + v.x + v.y;
  o.w = excl + v.x + v.y + v.z;
  if (base + 3 < N) *(int4*)(offs + base) = o;
  else {
    if (base + 0 < N) offs[base + 0] = o.x;
    if (base + 1 < N) offs[base + 1] = o.y;
    if (base + 2 < N) offs[base + 2] = o.z;
    if (base + 3 < N) offs[base + 3] = o.w;
  }
  if (t == 255) bsum[blockIdx.x] = wbase + incl;
}

// ---------------- tiny scan2: bbase[t] = exclusive prefix of bsum; offs[N] = bsum[nb-1] ----------------
__global__ void k_scan2(const int* __restrict__ bsum, int* __restrict__ bbase,
                        int* __restrict__ offs, int nb, int N) {
  int t = threadIdx.x;  // 64
  int v = (t < nb) ? bsum[t] : 0;
  int incl = v;
#pragma unroll
  for (int off = 1; off < 64; off <<= 1) {
    int u = __shfl_up(incl, off);
    if (t >= off) incl += u;
  }
  if (t < 64) bbase[t] = incl - v;
  if (t == nb - 1) offs[N] = v;   // so offs[N] + bbase[N>>10] == E
}

// ---------------- CSR build: csr[pos] = (src<<16) | fp16(dinv[src]), 2 edges/thread ----------------
__global__ void k_build(const int* __restrict__ src, const int* __restrict__ dst,
                        const unsigned short* __restrict__ rank,
                        const int* __restrict__ offs, const int* __restrict__ bbase,
                        const float* __restrict__ dinv,
                        unsigned* __restrict__ csr, int E) {
  int i = blockIdx.x * blockDim.x + threadIdx.x;
  int e = i * 2;
  if (e + 1 < E) {
    int2 s2 = *(const int2*)(src + e);
    int2 d2 = *(const int2*)(dst + e);
    unsigned rr = *(const unsigned*)(rank + e);
    int pos0 = offs[d2.x] + bbase[d2.x >> 10] + (int)(rr & 0xffffu);
    int pos1 = offs[d2.y] + bbase[d2.y >> 10] + (int)(rr >> 16);
    unsigned v0 = ((unsigned)s2.x << 16) | f2h_bits(dinv[s2.x]);
    unsigned v1 = ((unsigned)s2.y << 16) | f2h_bits(dinv[s2.y]);
    __builtin_nontemporal_store(v0, &csr[pos0]);
    __builtin_nontemporal_store(v1, &csr[pos1]);
  } else if (e < E) {
    int s = src[e], d = dst[e];
    int pos = offs[d] + bbase[d >> 10] + (int)rank[e];
    unsigned v = ((unsigned)s << 16) | f2h_bits(dinv[s]);
    __builtin_nontemporal_store(v, &csr[pos]);
  }
}

// ---------------- CSR gather C=64: 2 nodes/wave (32 lanes each, 4 edge-groups) ----------------
__global__ __launch_bounds__(256) void
k_gather64(const int* __restrict__ offs, const int* __restrict__ bbase,
           const unsigned* __restrict__ csr, const float* __restrict__ dinv,
           const _Float16* __restrict__ xw, _Float16* __restrict__ out, int N) {
  constexpr int C = 64;
  int wave = (int)((blockIdx.x * (size_t)blockDim.x + threadIdx.x) >> 6);
  int lane = threadIdx.x & 63;
  int half = lane >> 5;
  int node = wave * 2 + half;
  if (node >= N) return;
  int l32   = lane & 31;
  int group = l32 >> 3;      // 4 edge-groups of 8 lanes
  int sub   = l32 & 7;
  int ch0   = sub * 8;
  int hb    = half << 5;
  float dv = dinv[node];
  int j0 = offs[node] + bbase[node >> 10];
  int j1 = offs[node + 1] + bbase[(node + 1) >> 10];

  float acc[8];
  if (group == 0) {
    half8 v = *(const half8*)(xw + (size_t)node * C + ch0);
    float sc = dv * dv;
#pragma unroll
    for (int k = 0; k < 8; ++k) acc[k] = (float)v[k] * sc;
  } else {
#pragma unroll
    for (int k = 0; k < 8; ++k) acc[k] = 0.0f;
  }

  for (int base = j0; base < j1; base += 32) {
    int myj = base + l32;
    unsigned u_l = 0;
    if (myj < j1) u_l = csr[myj];
    int cnt = min(32, j1 - base);
    for (int k = 0; k < cnt; k += 4) {
      unsigned u = (unsigned)__shfl((int)u_l, hb + k + group);
      if (u != 0) {
        int   s = (int)(u >> 16);
        float c = h_bits2f(u) * dv;
        half8 v = *(const half8*)(xw + (size_t)s * C + ch0);
#pragma unroll
        for (int k2 = 0; k2 < 8; ++k2) acc[k2] = fmaf((float)v[k2], c, acc[k2]);
      }
    }
  }

#pragma unroll
  for (int off = 8; off < 32; off <<= 1) {
#pragma unroll
    for (int k = 0; k < 8; ++k) acc[k] += __shfl_xor(acc[k], off);
  }

  if (group == 0) {
    half8 o;
#pragma unroll
    for (int k = 0; k < 8; ++k) o[k] = (_Float16)acc[k];
    *(half8*)(out + (size_t)node * C + ch0) = o;
  }
}

// ---------------- fused MFMA GEMM + head projection ----------------
__global__ __launch_bounds__(256) void
k_mgemm_z(const _Float16* __restrict__ A, const _Float16* __restrict__ Wf,
          const float* __restrict__ bias, const float* __restrict__ Wz8,
          float* __restrict__ z, int M) {
  constexpr int K = DIN, NOUT = H1;
  constexpr int NC = NOUT / 16;   // 16
  constexpr int NT = K / 32;      // 2
  const int wave = threadIdx.x >> 6;
  const int lane = threadIdx.x & 63;
  const int rowbase = blockIdx.x * 128 + wave * 32;
  if (rowbase >= M) return;
  const int r  = lane & 15;
  const int kb = lane >> 4;
  int row0 = rowbase + r;       if (row0 >= M) row0 = M - 1;
  int row1 = rowbase + 16 + r;  if (row1 >= M) row1 = M - 1;
  const _Float16* a0p = A + (size_t)row0 * K + kb * 8;
  const _Float16* a1p = A + (size_t)row1 * K + kb * 8;

  f32x4 acc[2][NC];
#pragma unroll
  for (int rb = 0; rb < 2; ++rb)
#pragma unroll
    for (int c = 0; c < NC; ++c) acc[rb][c] = (f32x4)0.0f;

#pragma unroll
  for (int t = 0; t < NT; ++t) {
    half8 a0 = *(const half8*)(a0p + t * 32);
    half8 a1 = *(const half8*)(a1p + t * 32);
#pragma unroll
    for (int c = 0; c < NC; ++c) {
      half8 bf = ((const half8*)Wf)[(size_t)(c * NT + t) * 64 + lane];
      acc[0][c] = __builtin_amdgcn_mfma_f32_16x16x32_f16(a0, bf, acc[0][c], 0, 0, 0);
      acc[1][c] = __builtin_amdgcn_mfma_f32_16x16x32_f16(a1, bf, acc[1][c], 0, 0, 0);
    }
  }

  float zc[2][4][6];
#pragma unroll
  for (int rb = 0; rb < 2; ++rb)
#pragma unroll
    for (int j = 0; j < 4; ++j)
#pragma unroll
      for (int ch = 0; ch < 6; ++ch) zc[rb][j][ch] = 0.0f;

#pragma unroll
  for (int c = 0; c < NC; ++c) {
    int col = c * 16 + r;
    const float* wp = Wz8 + col * 8;
    float4 w0 = *(const float4*)wp;
    float2 w1 = *(const float2*)(wp + 4);
    float bv = bias[col];
#pragma unroll
    for (int rb = 0; rb < 2; ++rb) {
#pragma unroll
      for (int j = 0; j < 4; ++j) {
        float hv = fmaxf(acc[rb][c][j] + bv, 0.0f);
        zc[rb][j][0] = fmaf(hv, w0.x, zc[rb][j][0]);
        zc[rb][j][1] = fmaf(hv, w0.y, zc[rb][j][1]);
        zc[rb][j][2] = fmaf(hv, w0.z, zc[rb][j][2]);
        zc[rb][j][3] = fmaf(hv, w0.w, zc[rb][j][3]);
        zc[rb][j][4] = fmaf(hv, w1.x, zc[rb][j][4]);
        zc[rb][j][5] = fmaf(hv, w1.y, zc[rb][j][5]);
      }
    }
  }

#pragma unroll
  for (int off = 1; off < 16; off <<= 1) {
#pragma unroll
    for (int rb = 0; rb < 2; ++rb)
#pragma unroll
      for (int j = 0; j < 4; ++j)
#pragma unroll
        for (int ch = 0; ch < 6; ++ch)
          zc[rb][j][ch] += __shfl_xor(zc[rb][j][ch], off);
  }

  if (r == 0) {
#pragma unroll
    for (int rb = 0; rb < 2; ++rb) {
      int growbase = rowbase + rb * 16 + kb * 4;
#pragma unroll
      for (int j = 0; j < 4; ++j) {
        int grow = growbase + j;
        if (grow < M) {
          float4 lo = make_float4(zc[rb][j][0], zc[rb][j][1], zc[rb][j][2], zc[rb][j][3]);
          float4 hi = make_float4(zc[rb][j][4], zc[rb][j][5], 0.0f, 0.0f);
          *(float4*)(z + (size_t)grow * 8)     = lo;
          *(float4*)(z + (size_t)grow * 8 + 4) = hi;
        }
      }
    }
  }
}

// ---------------- aggregate z (C=8 fp32): 4 nodes per wave -> node_out, p, q ----------------
__global__ __launch_bounds__(256) void
k_gatherz(const int* __restrict__ offs, const int* __restrict__ bbase,
          const unsigned* __restrict__ csr, const float* __restrict__ dinv,
          const float* __restrict__ z, const float* __restrict__ consts,
          float* __restrict__ node_out, float* __restrict__ p, float* __restrict__ q,
          int N) {
  int wave = (int)((blockIdx.x * (size_t)blockDim.x + threadIdx.x) >> 6);
  int lane = threadIdx.x & 63;
  int quad = lane >> 4;           // 0..3
  int node = wave * 4 + quad;
  if (node >= N) return;
  int l16   = lane & 15;
  int group = l16 >> 1;           // 8 edge-groups per node
  int sub   = l16 & 1;            // float4 half of the z row
  int hb    = quad << 4;
  float dv = dinv[node];
  int j0 = offs[node] + bbase[node >> 10];
  int j1 = offs[node + 1] + bbase[(node + 1) >> 10];

  float4 acc = make_float4(0.0f, 0.0f, 0.0f, 0.0f);
  if (group == 0) {
    float4 v = *(const float4*)(z + (size_t)node * 8 + sub * 4);
    float sc = dv * dv;
    acc = make_float4(v.x * sc, v.y * sc, v.z * sc, v.w * sc);
  }

  for (int base = j0; base < j1; base += 16) {
    int myj = base + l16;
    unsigned u_l = 0;
    if (myj < j1) u_l = csr[myj];
    int cnt = min(16, j1 - base);
    for (int k = 0; k < cnt; k += 8) {
      unsigned u = (unsigned)__shfl((int)u_l, hb + k + group);
      if (u != 0) {
        int   s = (int)(u >> 16);
        float c = h_bits2f(u) * dv;
        float4 v = *(const float4*)(z + (size_t)s * 8 + sub * 4);
        acc.x = fmaf(v.x, c, acc.x);
        acc.y = fmaf(v.y, c, acc.y);
        acc.z = fmaf(v.z, c, acc.z);
        acc.w = fmaf(v.w, c, acc.w);
      }
    }
  }

#pragma unroll
  for (int off = 2; off < 16; off <<= 1) {
    acc.x += __shfl_xor(acc.x, off);
    acc.y += __shfl_xor(acc.y, off);
    acc.z += __shfl_xor(acc.z, off);
    acc.w += __shfl_xor(acc.w, off);
  }

  if (l16 == 0) {
    float2 no = make_float2(acc.x + consts[0], acc.y + consts[1]);
    float2 pp = make_float2(acc.z + consts[2], acc.w + consts[3]);
    *(float2*)(node_out + (size_t)node * 2) = no;
    *(float2*)(p + (size_t)node * 2) = pp;
  } else if (l16 == 1) {
    float2 qq = make_float2(acc.x + consts[4], acc.y + consts[5]);
    *(float2*)(q + (size_t)node * 2) = qq;
  }
}

// ---------------- edge output: 4 edges per thread ----------------
__global__ void k_edge(const int* __restrict__ src, const int* __restrict__ dst,
                       const float* __restrict__ p, const float* __restrict__ q,
                       const float* __restrict__ eb, float* __restrict__ eout, int E) {
  int i = blockIdx.x * blockDim.x + threadIdx.x;
  int e = i * 4;
  float e0 = eb[0], e1 = eb[1];
  if (e + 3 < E) {
    int4 s4 = *(const int4*)(src + e);
    int4 d4 = *(const int4*)(dst + e);
    float2 P0 = *(const float2*)(p + (size_t)s4.x * 2);
    float2 Q0 = *(const float2*)(q + (size_t)d4.x * 2);
    float2 P1 = *(const float2*)(p + (size_t)s4.y * 2);
    float2 Q1 = *(const float2*)(q + (size_t)d4.y * 2);
    float2 P2 = *(const float2*)(p + (size_t)s4.z * 2);
    float2 Q2 = *(const float2*)(q + (size_t)d4.z * 2);
    float2 P3 = *(const float2*)(p + (size_t)s4.w * 2);
    float2 Q3 = *(const float2*)(q + (size_t)d4.w * 2);
    float4 oa, ob;
    oa.x = P0.x + Q0.x + e0;  oa.y = P0.y + Q0.y + e1;
    oa.z = P1.x + Q1.x + e0;  oa.w = P1.y + Q1.y + e1;
    ob.x = P2.x + Q2.x + e0;  ob.y = P2.y + Q2.y + e1;
    ob.z = P3.x + Q3.x + e0;  ob.w = P3.y + Q3.y + e1;
    *(float4*)(eout + (size_t)e * 2)     = oa;
    *(float4*)(eout + (size_t)e * 2 + 4) = ob;
  } else {
    for (; e < E; ++e) {
      int s = src[e], d = dst[e];
      float2 P = *(const float2*)(p + (size_t)s * 2);
      float2 Q = *(const float2*)(q + (size_t)d * 2);
      float2 o;
      o.x = P.x + Q.x + e0;
      o.y = P.y + Q.y + e1;
      *(float2*)(eout + (size_t)e * 2) = o;
    }
  }
}

extern "C" void kernel_launch(void* const* d_in, const int* in_sizes, int n_in,
                              void* d_out, int out_size, void* d_ws, size_t ws_size,
                              hipStream_t stream) {
  const float* x   = (const float*)d_in[0];
  const int*   ei  = (const int*)d_in[1];
  const float* W1  = (const float*)d_in[2];
  const float* b1  = (const float*)d_in[3];
  const float* W2  = (const float*)d_in[4];
  const float* b2  = (const float*)d_in[5];
  const float* nW  = (const float*)d_in[6];
  const float* nb  = (const float*)d_in[7];
  const float* eW  = (const float*)d_in[8];
  const float* eb  = (const float*)d_in[9];

  const int N = in_sizes[0] / DIN;   // 50000
  const int E = in_sizes[1] / 2;     // 800000
  const int* src = ei;
  const int* dst = ei + E;

  // ---- workspace layout ----
  float* fws   = (float*)d_ws;
  float* dinv  = fws;                            // N
  float* p     = dinv + N;                       // 2N
  float* q     = p + 2 * (size_t)N;              // 2N
  float* z     = q + 2 * (size_t)N;              // 8N
  float* Wz8   = z + 8 * (size_t)N;              // 2048
  float* consts = Wz8 + 2048;                    // 8
  _Float16* xh    = (_Float16*)(consts + 8);     // 64N
  _Float16* aggxh = xh + (size_t)DIN * N;        // 64N
  _Float16* Wf1   = aggxh + (size_t)DIN * N;     // 16384
  int* hist = (int*)(Wf1 + DIN * H1);            // N
  int* offs = hist + N;                          // N+1
  int* bsum = offs + N + 1;                      // 64
  int* bbase = bsum + 64;                        // 64
  unsigned short* rank = (unsigned short*)(bbase + 64);  // E (u16)
  unsigned* csr = (unsigned*)(rank + E);                 // E (u32 packed)

  float* node_out = (float*)d_out;                   // 2N
  float* edge_out = (float*)d_out + 2 * (size_t)N;   // 2E

  const int nb_blk = (N + 1023) / 1024;          // 49
  const int nvec8  = N * DIN / 8;

  const int NB0 = (N + 255) / 256;
  const int NB1 = NB0 + (nvec8 + 255) / 256;
  const int NB2 = NB1 + (DIN * H1 + 255) / 256;
  const int NBP = NB2 + 1;

  // ---- prep + CSR build ----
  k_prep<<<NBP, 256, 0, stream>>>(hist, N, x, xh, nvec8, W1, Wf1,
                                  W2, nW, nb, eW, b2, Wz8, consts, NB0, NB1, NB2);
  k_hist<<<((E + 1) / 2 + 255) / 256, 256, 0, stream>>>(dst, hist, rank, E);
  k_scan1<<<nb_blk, 256, 0, stream>>>(hist, offs, bsum, dinv, N);
  k_scan2<<<1, 64, 0, stream>>>(bsum, bbase, offs, nb_blk, N);
  k_build<<<((E + 1) / 2 + 255) / 256, 256, 0, stream>>>(src, dst, rank, offs, bbase, dinv, csr, E);

  // ---- layer 1 aggregate, then fused transform + head projection ----
  {
    int waves = (N + 1) / 2;
    k_gather64<<<(waves + 3) / 4, 256, 0, stream>>>(offs, bbase, csr, dinv, xh, aggxh, N);
  }
  k_mgemm_z<<<(N + 127) / 128, 256, 0, stream>>>(aggxh, Wf1, b1, Wz8, z, N);

  // ---- aggregate 6-dim z -> node_out, p, q ----
  {
    int waves = (N + 3) / 4;
    k_gatherz<<<(waves + 3) / 4, 256, 0, stream>>>(offs, bbase, csr, dinv, z, consts, node_out, p, q, N);
  }

  // ---- edge output ----
  k_edge<<<((E + 3) / 4 + 255) / 256, 256, 0, stream>>>(src, dst, p, q, eb, edge_out, E);
}

// Round 13
// 129.670 us; speedup vs baseline: 1.8111x; 1.0891x over previous
//
#include <hip/hip_runtime.h>

static constexpr int DIN = 64;
static constexpr int H1  = 256;
static constexpr int H2  = 128;

using half8 = _Float16 __attribute__((ext_vector_type(8)));
using f32x4 = float __attribute__((ext_vector_type(4)));

__device__ __forceinline__ unsigned short f2h_bits(float f) {
  _Float16 h = (_Float16)f;
  unsigned short u;
  __builtin_memcpy(&u, &h, 2);
  return u;
}
__device__ __forceinline__ float h_bits2f(unsigned u) {
  unsigned short us = (unsigned short)(u & 0xffffu);
  _Float16 h;
  __builtin_memcpy(&h, &us, 2);
  return (float)h;
}

// ---------------- fused prep: zero hist | cast x->fp16 | W1 frag | Wz8 fused-head ----------------
__global__ __launch_bounds__(256) void
k_prep(int* __restrict__ hist, int N,
       const float* __restrict__ x, _Float16* __restrict__ xh, int nvec8,
       const float* __restrict__ W1, _Float16* __restrict__ Wf1,
       const float* __restrict__ W2, const float* __restrict__ nW,
       const float* __restrict__ nb, const float* __restrict__ eW,
       const float* __restrict__ b2, float* __restrict__ Wz8,
       float* __restrict__ consts,
       int NB0, int NB1, int NB2) {
  const int b = blockIdx.x;
  const int t = threadIdx.x;
  if (b < NB0) {
    int i = b * 256 + t;
    if (i < N) hist[i] = 0;
  } else if (b < NB1) {
    int i = (b - NB0) * 256 + t;
    if (i < nvec8) {
      const float4* x4 = (const float4*)x;
      float4 a = x4[i * 2 + 0];
      float4 bb = x4[i * 2 + 1];
      half8 h;
      h[0] = (_Float16)a.x; h[1] = (_Float16)a.y; h[2] = (_Float16)a.z; h[3] = (_Float16)a.w;
      h[4] = (_Float16)bb.x; h[5] = (_Float16)bb.y; h[6] = (_Float16)bb.z; h[7] = (_Float16)bb.w;
      *(half8*)(xh + (size_t)i * 8) = h;
    }
  } else if (b < NB2) {
    int i = (b - NB1) * 256 + t;
    if (i < DIN * H1) {
      int j    = i & 7;
      int lane = (i >> 3) & 63;
      int rest = i >> 9;
      int tt   = rest % (DIN / 32);
      int c    = rest / (DIN / 32);
      int k    = tt * 32 + (lane >> 4) * 8 + j;
      int col  = c * 16 + (lane & 15);
      Wf1[i] = (_Float16)W1[k * H1 + col];
    }
  } else {
    int k = t;   // 0..255
    float acc[6] = {0, 0, 0, 0, 0, 0};
    for (int m = 0; m < H2; ++m) {
      float w = W2[k * H2 + m];
      acc[0] = fmaf(w, nW[m * 2 + 0], acc[0]);
      acc[1] = fmaf(w, nW[m * 2 + 1], acc[1]);
      acc[2] = fmaf(w, eW[m * 2 + 0], acc[2]);
      acc[3] = fmaf(w, eW[m * 2 + 1], acc[3]);
      acc[4] = fmaf(w, eW[(H2 + m) * 2 + 0], acc[4]);
      acc[5] = fmaf(w, eW[(H2 + m) * 2 + 1], acc[5]);
    }
#pragma unroll
    for (int c = 0; c < 6; ++c) Wz8[k * 8 + c] = acc[c];
    Wz8[k * 8 + 6] = 0.0f; Wz8[k * 8 + 7] = 0.0f;
    if (k == 0) {
      float c0 = nb[0], c1 = nb[1], c2 = 0, c3 = 0, c4 = 0, c5 = 0;
      for (int m = 0; m < H2; ++m) {
        float bv = b2[m];
        c0 = fmaf(bv, nW[m * 2 + 0], c0);
        c1 = fmaf(bv, nW[m * 2 + 1], c1);
        c2 = fmaf(bv, eW[m * 2 + 0], c2);
        c3 = fmaf(bv, eW[m * 2 + 1], c3);
        c4 = fmaf(bv, eW[(H2 + m) * 2 + 0], c4);
        c5 = fmaf(bv, eW[(H2 + m) * 2 + 1], c5);
      }
      consts[0] = c0; consts[1] = c1; consts[2] = c2;
      consts[3] = c3; consts[4] = c4; consts[5] = c5;
      consts[6] = 0.0f; consts[7] = 0.0f;
    }
  }
}

// ---------------- degree histogram + per-edge rank (4 edges/thread) ----------------
__global__ void k_hist(const int* __restrict__ dst, int* __restrict__ hist,
                       unsigned short* __restrict__ rank, int E) {
  int i = blockIdx.x * blockDim.x + threadIdx.x;
  int e = i * 4;
  if (e + 3 < E) {
    int4 d4 = *(const int4*)(dst + e);
    int r0 = atomicAdd(&hist[d4.x], 1);
    int r1 = atomicAdd(&hist[d4.y], 1);
    int r2 = atomicAdd(&hist[d4.z], 1);
    int r3 = atomicAdd(&hist[d4.w], 1);
    unsigned pk0 = (unsigned)(r0 & 0xffff) | ((unsigned)(r1 & 0xffff) << 16);
    unsigned pk1 = (unsigned)(r2 & 0xffff) | ((unsigned)(r3 & 0xffff) << 16);
    *(unsigned*)(rank + e)     = pk0;
    *(unsigned*)(rank + e + 2) = pk1;
  } else {
    for (; e < E; ++e) {
      int r = atomicAdd(&hist[dst[e]], 1);
      rank[e] = (unsigned short)r;
    }
  }
}

// ---------------- scan phase 1 (+ fused dinv); offs stays BLOCK-LOCAL ----------------
__global__ void k_scan1(const int* __restrict__ hist, int* __restrict__ offs,
                        int* __restrict__ bsum, float* __restrict__ dinv, int N) {
  __shared__ int ws[4];
  const int t = threadIdx.x;
  const int base = blockIdx.x * 1024 + t * 4;
  int4 v = make_int4(0, 0, 0, 0);
  if (base + 3 < N) v = *(const int4*)(hist + base);
  else {
    if (base + 0 < N) v.x = hist[base + 0];
    if (base + 1 < N) v.y = hist[base + 1];
    if (base + 2 < N) v.z = hist[base + 2];
    if (base + 3 < N) v.w = hist[base + 3];
  }
  if (base + 3 < N) {
    float4 dv = make_float4(rsqrtf((float)v.x + 1.0f), rsqrtf((float)v.y + 1.0f),
                            rsqrtf((float)v.z + 1.0f), rsqrtf((float)v.w + 1.0f));
    *(float4*)(dinv + base) = dv;
  } else {
    if (base + 0 < N) dinv[base + 0] = rsqrtf((float)v.x + 1.0f);
    if (base + 1 < N) dinv[base + 1] = rsqrtf((float)v.y + 1.0f);
    if (base + 2 < N) dinv[base + 2] = rsqrtf((float)v.z + 1.0f);
    if (base + 3 < N) dinv[base + 3] = rsqrtf((float)v.w + 1.0f);
  }
  int tsum = v.x + v.y + v.z + v.w;
  int lane = t & 63, wid = t >> 6;
  int incl = tsum;
#pragma unroll
  for (int off = 1; off < 64; off <<= 1) {
    int u = __shfl_up(incl, off);
    if (lane >= off) incl += u;
  }
  if (lane == 63) ws[wid] = incl;
  __syncthreads();
  int wbase = 0;
  for (int w = 0; w < wid; ++w) wbase += ws[w];
  int excl = wbase + incl - tsum;
  int4 o;
  o.x = excl;
  o.y = excl + v.x;
  o.z = excl + v.x + v.y;
  o.w = excl + v.x + v.y + v.z;
  if (base + 3 < N) *(int4*)(offs + base) = o;
  else {
    if (base + 0 < N) offs[base + 0] = o.x;
    if (base + 1 < N) offs[base + 1] = o.y;
    if (base + 2 < N) offs[base + 2] = o.z;
    if (base + 3 < N) offs[base + 3] = o.w;
  }
  if (t == 255) bsum[blockIdx.x] = wbase + incl;
}

// ---------------- tiny scan2 ----------------
__global__ void k_scan2(const int* __restrict__ bsum, int* __restrict__ bbase,
                        int* __restrict__ offs, int nb, int N) {
  int t = threadIdx.x;  // 64
  int v = (t < nb) ? bsum[t] : 0;
  int incl = v;
#pragma unroll
  for (int off = 1; off < 64; off <<= 1) {
    int u = __shfl_up(incl, off);
    if (t >= off) incl += u;
  }
  if (t < 64) bbase[t] = incl - v;
  if (t == nb - 1) offs[N] = v;
}

// ---------------- CSR build: csr[pos] = (src<<16) | fp16(dinv[src]), 4 edges/thread ----------------
__global__ void k_build(const int* __restrict__ src, const int* __restrict__ dst,
                        const unsigned short* __restrict__ rank,
                        const int* __restrict__ offs, const int* __restrict__ bbase,
                        const float* __restrict__ dinv,
                        unsigned* __restrict__ csr, int E) {
  int i = blockIdx.x * blockDim.x + threadIdx.x;
  int e = i * 4;
  if (e + 3 < E) {
    int4 s4 = *(const int4*)(src + e);
    int4 d4 = *(const int4*)(dst + e);
    unsigned rr0 = *(const unsigned*)(rank + e);
    unsigned rr1 = *(const unsigned*)(rank + e + 2);
    int pos0 = offs[d4.x] + bbase[d4.x >> 10] + (int)(rr0 & 0xffffu);
    int pos1 = offs[d4.y] + bbase[d4.y >> 10] + (int)(rr0 >> 16);
    int pos2 = offs[d4.z] + bbase[d4.z >> 10] + (int)(rr1 & 0xffffu);
    int pos3 = offs[d4.w] + bbase[d4.w >> 10] + (int)(rr1 >> 16);
    unsigned v0 = ((unsigned)s4.x << 16) | f2h_bits(dinv[s4.x]);
    unsigned v1 = ((unsigned)s4.y << 16) | f2h_bits(dinv[s4.y]);
    unsigned v2 = ((unsigned)s4.z << 16) | f2h_bits(dinv[s4.z]);
    unsigned v3 = ((unsigned)s4.w << 16) | f2h_bits(dinv[s4.w]);
    csr[pos0] = v0;
    csr[pos1] = v1;
    csr[pos2] = v2;
    csr[pos3] = v3;
  } else {
    for (; e < E; ++e) {
      int s = src[e], d = dst[e];
      int pos = offs[d] + bbase[d >> 10] + (int)rank[e];
      csr[pos] = ((unsigned)s << 16) | f2h_bits(dinv[s]);
    }
  }
}

// ---------------- CSR gather C=64: 2 nodes/wave, 2-deep pipelined inner loop ----------------
__global__ __launch_bounds__(256) void
k_gather64(const int* __restrict__ offs, const int* __restrict__ bbase,
           const unsigned* __restrict__ csr, const float* __restrict__ dinv,
           const _Float16* __restrict__ xw, _Float16* __restrict__ out, int N) {
  constexpr int C = 64;
  int wave = (int)((blockIdx.x * (size_t)blockDim.x + threadIdx.x) >> 6);
  int lane = threadIdx.x & 63;
  int half = lane >> 5;
  int node = wave * 2 + half;
  if (node >= N) return;
  int l32   = lane & 31;
  int group = l32 >> 3;      // 4 edge-groups of 8 lanes
  int sub   = l32 & 7;
  int ch0   = sub * 8;
  int hb    = half << 5;
  float dv = dinv[node];
  int j0 = offs[node] + bbase[node >> 10];
  int j1 = offs[node + 1] + bbase[(node + 1) >> 10];

  float acc[8];
  if (group == 0) {
    half8 v = *(const half8*)(xw + (size_t)node * C + ch0);
    float sc = dv * dv;
#pragma unroll
    for (int k = 0; k < 8; ++k) acc[k] = (float)v[k] * sc;
  } else {
#pragma unroll
    for (int k = 0; k < 8; ++k) acc[k] = 0.0f;
  }

  for (int base = j0; base < j1; base += 32) {
    int myj = base + l32;
    unsigned u_l = 0;
    if (myj < j1) u_l = csr[myj];
    int cnt = min(32, j1 - base);
    // 2-deep: each group handles edges (k+group) and (k+4+group) per iteration
    for (int k = 0; k < cnt; k += 8) {
      unsigned ua = (unsigned)__shfl((int)u_l, hb + k + group);
      unsigned ub = (unsigned)__shfl((int)u_l, hb + k + 4 + group);
      half8 va, vb;
      bool ba = (ua != 0), bb = (ub != 0);
      if (ba) va = *(const half8*)(xw + (size_t)(ua >> 16) * C + ch0);
      if (bb) vb = *(const half8*)(xw + (size_t)(ub >> 16) * C + ch0);
      if (ba) {
        float c = h_bits2f(ua) * dv;
#pragma unroll
        for (int k2 = 0; k2 < 8; ++k2) acc[k2] = fmaf((float)va[k2], c, acc[k2]);
      }
      if (bb) {
        float c = h_bits2f(ub) * dv;
#pragma unroll
        for (int k2 = 0; k2 < 8; ++k2) acc[k2] = fmaf((float)vb[k2], c, acc[k2]);
      }
    }
  }

#pragma unroll
  for (int off = 8; off < 32; off <<= 1) {
#pragma unroll
    for (int k = 0; k < 8; ++k) acc[k] += __shfl_xor(acc[k], off);
  }

  if (group == 0) {
    half8 o;
#pragma unroll
    for (int k = 0; k < 8; ++k) o[k] = (_Float16)acc[k];
    *(half8*)(out + (size_t)node * C + ch0) = o;
  }
}

// ---------------- fused MFMA GEMM + head projection ----------------
__global__ __launch_bounds__(256) void
k_mgemm_z(const _Float16* __restrict__ A, const _Float16* __restrict__ Wf,
          const float* __restrict__ bias, const float* __restrict__ Wz8,
          float* __restrict__ z, int M) {
  constexpr int K = DIN, NOUT = H1;
  constexpr int NC = NOUT / 16;   // 16
  constexpr int NT = K / 32;      // 2
  const int wave = threadIdx.x >> 6;
  const int lane = threadIdx.x & 63;
  const int rowbase = blockIdx.x * 128 + wave * 32;
  if (rowbase >= M) return;
  const int r  = lane & 15;
  const int kb = lane >> 4;
  int row0 = rowbase + r;       if (row0 >= M) row0 = M - 1;
  int row1 = rowbase + 16 + r;  if (row1 >= M) row1 = M - 1;
  const _Float16* a0p = A + (size_t)row0 * K + kb * 8;
  const _Float16* a1p = A + (size_t)row1 * K + kb * 8;

  f32x4 acc[2][NC];
#pragma unroll
  for (int rb = 0; rb < 2; ++rb)
#pragma unroll
    for (int c = 0; c < NC; ++c) acc[rb][c] = (f32x4)0.0f;

#pragma unroll
  for (int t = 0; t < NT; ++t) {
    half8 a0 = *(const half8*)(a0p + t * 32);
    half8 a1 = *(const half8*)(a1p + t * 32);
#pragma unroll
    for (int c = 0; c < NC; ++c) {
      half8 bf = ((const half8*)Wf)[(size_t)(c * NT + t) * 64 + lane];
      acc[0][c] = __builtin_amdgcn_mfma_f32_16x16x32_f16(a0, bf, acc[0][c], 0, 0, 0);
      acc[1][c] = __builtin_amdgcn_mfma_f32_16x16x32_f16(a1, bf, acc[1][c], 0, 0, 0);
    }
  }

  float zc[2][4][6];
#pragma unroll
  for (int rb = 0; rb < 2; ++rb)
#pragma unroll
    for (int j = 0; j < 4; ++j)
#pragma unroll
      for (int ch = 0; ch < 6; ++ch) zc[rb][j][ch] = 0.0f;

#pragma unroll
  for (int c = 0; c < NC; ++c) {
    int col = c * 16 + r;
    const float* wp = Wz8 + col * 8;
    float4 w0 = *(const float4*)wp;
    float2 w1 = *(const float2*)(wp + 4);
    float bv = bias[col];
#pragma unroll
    for (int rb = 0; rb < 2; ++rb) {
#pragma unroll
      for (int j = 0; j < 4; ++j) {
        float hv = fmaxf(acc[rb][c][j] + bv, 0.0f);
        zc[rb][j][0] = fmaf(hv, w0.x, zc[rb][j][0]);
        zc[rb][j][1] = fmaf(hv, w0.y, zc[rb][j][1]);
        zc[rb][j][2] = fmaf(hv, w0.z, zc[rb][j][2]);
        zc[rb][j][3] = fmaf(hv, w0.w, zc[rb][j][3]);
        zc[rb][j][4] = fmaf(hv, w1.x, zc[rb][j][4]);
        zc[rb][j][5] = fmaf(hv, w1.y, zc[rb][j][5]);
      }
    }
  }

#pragma unroll
  for (int off = 1; off < 16; off <<= 1) {
#pragma unroll
    for (int rb = 0; rb < 2; ++rb)
#pragma unroll
      for (int j = 0; j < 4; ++j)
#pragma unroll
        for (int ch = 0; ch < 6; ++ch)
          zc[rb][j][ch] += __shfl_xor(zc[rb][j][ch], off);
  }

  if (r == 0) {
#pragma unroll
    for (int rb = 0; rb < 2; ++rb) {
      int growbase = rowbase + rb * 16 + kb * 4;
#pragma unroll
      for (int j = 0; j < 4; ++j) {
        int grow = growbase + j;
        if (grow < M) {
          float4 lo = make_float4(zc[rb][j][0], zc[rb][j][1], zc[rb][j][2], zc[rb][j][3]);
          float4 hi = make_float4(zc[rb][j][4], zc[rb][j][5], 0.0f, 0.0f);
          *(float4*)(z + (size_t)grow * 8)     = lo;
          *(float4*)(z + (size_t)grow * 8 + 4) = hi;
        }
      }
    }
  }
}

// ---------------- aggregate z (C=8 fp32): 4 nodes per wave -> node_out, p, q ----------------
__global__ __launch_bounds__(256) void
k_gatherz(const int* __restrict__ offs, const int* __restrict__ bbase,
          const unsigned* __restrict__ csr, const float* __restrict__ dinv,
          const float* __restrict__ z, const float* __restrict__ consts,
          float* __restrict__ node_out, float* __restrict__ p, float* __restrict__ q,
          int N) {
  int wave = (int)((blockIdx.x * (size_t)blockDim.x + threadIdx.x) >> 6);
  int lane = threadIdx.x & 63;
  int quad = lane >> 4;           // 0..3
  int node = wave * 4 + quad;
  if (node >= N) return;
  int l16   = lane & 15;
  int group = l16 >> 1;           // 8 edge-groups per node
  int sub   = l16 & 1;            // float4 half of the z row
  int hb    = quad << 4;
  float dv = dinv[node];
  int j0 = offs[node] + bbase[node >> 10];
  int j1 = offs[node + 1] + bbase[(node + 1) >> 10];

  float4 acc = make_float4(0.0f, 0.0f, 0.0f, 0.0f);
  if (group == 0) {
    float4 v = *(const float4*)(z + (size_t)node * 8 + sub * 4);
    float sc = dv * dv;
    acc = make_float4(v.x * sc, v.y * sc, v.z * sc, v.w * sc);
  }

  for (int base = j0; base < j1; base += 16) {
    int myj = base + l16;
    unsigned u_l = 0;
    if (myj < j1) u_l = csr[myj];
    int cnt = min(16, j1 - base);
    for (int k = 0; k < cnt; k += 8) {
      unsigned u = (unsigned)__shfl((int)u_l, hb + k + group);
      if (u != 0) {
        int   s = (int)(u >> 16);
        float c = h_bits2f(u) * dv;
        float4 v = *(const float4*)(z + (size_t)s * 8 + sub * 4);
        acc.x = fmaf(v.x, c, acc.x);
        acc.y = fmaf(v.y, c, acc.y);
        acc.z = fmaf(v.z, c, acc.z);
        acc.w = fmaf(v.w, c, acc.w);
      }
    }
  }

#pragma unroll
  for (int off = 2; off < 16; off <<= 1) {
    acc.x += __shfl_xor(acc.x, off);
    acc.y += __shfl_xor(acc.y, off);
    acc.z += __shfl_xor(acc.z, off);
    acc.w += __shfl_xor(acc.w, off);
  }

  if (l16 == 0) {
    float2 no = make_float2(acc.x + consts[0], acc.y + consts[1]);
    float2 pp = make_float2(acc.z + consts[2], acc.w + consts[3]);
    *(float2*)(node_out + (size_t)node * 2) = no;
    *(float2*)(p + (size_t)node * 2) = pp;
  } else if (l16 == 1) {
    float2 qq = make_float2(acc.x + consts[4], acc.y + consts[5]);
    *(float2*)(q + (size_t)node * 2) = qq;
  }
}

// ---------------- edge output: 4 edges per thread ----------------
__global__ void k_edge(const int* __restrict__ src, const int* __restrict__ dst,
                       const float* __restrict__ p, const float* __restrict__ q,
                       const float* __restrict__ eb, float* __restrict__ eout, int E) {
  int i = blockIdx.x * blockDim.x + threadIdx.x;
  int e = i * 4;
  float e0 = eb[0], e1 = eb[1];
  if (e + 3 < E) {
    int4 s4 = *(const int4*)(src + e);
    int4 d4 = *(const int4*)(dst + e);
    float2 P0 = *(const float2*)(p + (size_t)s4.x * 2);
    float2 Q0 = *(const float2*)(q + (size_t)d4.x * 2);
    float2 P1 = *(const float2*)(p + (size_t)s4.y * 2);
    float2 Q1 = *(const float2*)(q + (size_t)d4.y * 2);
    float2 P2 = *(const float2*)(p + (size_t)s4.z * 2);
    float2 Q2 = *(const float2*)(q + (size_t)d4.z * 2);
    float2 P3 = *(const float2*)(p + (size_t)s4.w * 2);
    float2 Q3 = *(const float2*)(q + (size_t)d4.w * 2);
    float4 oa, ob;
    oa.x = P0.x + Q0.x + e0;  oa.y = P0.y + Q0.y + e1;
    oa.z = P1.x + Q1.x + e0;  oa.w = P1.y + Q1.y + e1;
    ob.x = P2.x + Q2.x + e0;  ob.y = P2.y + Q2.y + e1;
    ob.z = P3.x + Q3.x + e0;  ob.w = P3.y + Q3.y + e1;
    *(float4*)(eout + (size_t)e * 2)     = oa;
    *(float4*)(eout + (size_t)e * 2 + 4) = ob;
  } else {
    for (; e < E; ++e) {
      int s = src[e], d = dst[e];
      float2 P = *(const float2*)(p + (size_t)s * 2);
      float2 Q = *(const float2*)(q + (size_t)d * 2);
      float2 o;
      o.x = P.x + Q.x + e0;
      o.y = P.y + Q.y + e1;
      *(float2*)(eout + (size_t)e * 2) = o;
    }
  }
}

extern "C" void kernel_launch(void* const* d_in, const int* in_sizes, int n_in,
                              void* d_out, int out_size, void* d_ws, size_t ws_size,
                              hipStream_t stream) {
  const float* x   = (const float*)d_in[0];
  const int*   ei  = (const int*)d_in[1];
  const float* W1  = (const float*)d_in[2];
  const float* b1  = (const float*)d_in[3];
  const float* W2  = (const float*)d_in[4];
  const float* b2  = (const float*)d_in[5];
  const float* nW  = (const float*)d_in[6];
  const float* nb  = (const float*)d_in[7];
  const float* eW  = (const float*)d_in[8];
  const float* eb  = (const float*)d_in[9];

  const int N = in_sizes[0] / DIN;   // 50000
  const int E = in_sizes[1] / 2;     // 800000
  const int* src = ei;
  const int* dst = ei + E;

  // ---- workspace layout ----
  float* fws   = (float*)d_ws;
  float* dinv  = fws;                            // N
  float* p     = dinv + N;                       // 2N
  float* q     = p + 2 * (size_t)N;              // 2N
  float* z     = q + 2 * (size_t)N;              // 8N
  float* Wz8   = z + 8 * (size_t)N;              // 2048
  float* consts = Wz8 + 2048;                    // 8
  _Float16* xh    = (_Float16*)(consts + 8);     // 64N
  _Float16* aggxh = xh + (size_t)DIN * N;        // 64N
  _Float16* Wf1   = aggxh + (size_t)DIN * N;     // 16384
  int* hist = (int*)(Wf1 + DIN * H1);            // N
  int* offs = hist + N;                          // N+1
  int* bsum = offs + N + 1;                      // 64
  int* bbase = bsum + 64;                        // 64
  unsigned short* rank = (unsigned short*)(bbase + 64);  // E (u16)
  unsigned* csr = (unsigned*)(rank + E);                 // E (u32 packed)

  float* node_out = (float*)d_out;                   // 2N
  float* edge_out = (float*)d_out + 2 * (size_t)N;   // 2E

  const int nb_blk = (N + 1023) / 1024;          // 49
  const int nvec8  = N * DIN / 8;

  const int NB0 = (N + 255) / 256;
  const int NB1 = NB0 + (nvec8 + 255) / 256;
  const int NB2 = NB1 + (DIN * H1 + 255) / 256;
  const int NBP = NB2 + 1;

  // ---- prep + CSR build ----
  k_prep<<<NBP, 256, 0, stream>>>(hist, N, x, xh, nvec8, W1, Wf1,
                                  W2, nW, nb, eW, b2, Wz8, consts, NB0, NB1, NB2);
  k_hist<<<((E + 3) / 4 + 255) / 256, 256, 0, stream>>>(dst, hist, rank, E);
  k_scan1<<<nb_blk, 256, 0, stream>>>(hist, offs, bsum, dinv, N);
  k_scan2<<<1, 64, 0, stream>>>(bsum, bbase, offs, nb_blk, N);
  k_build<<<((E + 3) / 4 + 255) / 256, 256, 0, stream>>>(src, dst, rank, offs, bbase, dinv, csr, E);

  // ---- layer 1 aggregate, then fused transform + head projection ----
  {
    int waves = (N + 1) / 2;
    k_gather64<<<(waves + 3) / 4, 256, 0, stream>>>(offs, bbase, csr, dinv, xh, aggxh, N);
  }
  k_mgemm_z<<<(N + 127) / 128, 256, 0, stream>>>(aggxh, Wf1, b1, Wz8, z, N);

  // ---- aggregate 6-dim z -> node_out, p, q ----
  {
    int waves = (N + 3) / 4;
    k_gatherz<<<(waves + 3) / 4, 256, 0, stream>>>(offs, bbase, csr, dinv, z, consts, node_out, p, q, N);
  }

  // ---- edge output ----
  k_edge<<<((E + 3) / 4 + 255) / 256, 256, 0, stream>>>(src, dst, p, q, eb, edge_out, E);
}

// Round 14
// 128.719 us; speedup vs baseline: 1.8245x; 1.0074x over previous
//
#include <hip/hip_runtime.h>

static constexpr int DIN = 64;
static constexpr int H1  = 256;
static constexpr int H2  = 128;

using half8 = _Float16 __attribute__((ext_vector_type(8)));
using f32x4 = float __attribute__((ext_vector_type(4)));

__device__ __forceinline__ unsigned short f2h_bits(float f) {
  _Float16 h = (_Float16)f;
  unsigned short u;
  __builtin_memcpy(&u, &h, 2);
  return u;
}
__device__ __forceinline__ float h_bits2f(unsigned u) {
  unsigned short us = (unsigned short)(u & 0xffffu);
  _Float16 h;
  __builtin_memcpy(&h, &us, 2);
  return (float)h;
}

// ---------------- fused prep: zero hist+done | cast x->fp16 | W1 frag | Wz8 fused-head ----------------
__global__ __launch_bounds__(256) void
k_prep(int* __restrict__ hist, int N,
       const float* __restrict__ x, _Float16* __restrict__ xh, int nvec8,
       const float* __restrict__ W1, _Float16* __restrict__ Wf1,
       const float* __restrict__ W2, const float* __restrict__ nW,
       const float* __restrict__ nb, const float* __restrict__ eW,
       const float* __restrict__ b2, float* __restrict__ Wz8,
       float* __restrict__ consts, int* __restrict__ done,
       int NB0, int NB1, int NB2) {
  const int b = blockIdx.x;
  const int t = threadIdx.x;
  if (b < NB0) {
    int i = b * 256 + t;
    if (i < N) hist[i] = 0;
    if (b == 0 && t == 0) *done = 0;
  } else if (b < NB1) {
    int i = (b - NB0) * 256 + t;
    if (i < nvec8) {
      const float4* x4 = (const float4*)x;
      float4 a = x4[i * 2 + 0];
      float4 bb = x4[i * 2 + 1];
      half8 h;
      h[0] = (_Float16)a.x; h[1] = (_Float16)a.y; h[2] = (_Float16)a.z; h[3] = (_Float16)a.w;
      h[4] = (_Float16)bb.x; h[5] = (_Float16)bb.y; h[6] = (_Float16)bb.z; h[7] = (_Float16)bb.w;
      *(half8*)(xh + (size_t)i * 8) = h;
    }
  } else if (b < NB2) {
    int i = (b - NB1) * 256 + t;
    if (i < DIN * H1) {
      int j    = i & 7;
      int lane = (i >> 3) & 63;
      int rest = i >> 9;
      int tt   = rest % (DIN / 32);
      int c    = rest / (DIN / 32);
      int k    = tt * 32 + (lane >> 4) * 8 + j;
      int col  = c * 16 + (lane & 15);
      Wf1[i] = (_Float16)W1[k * H1 + col];
    }
  } else {
    int k = t;   // 0..255
    float acc[6] = {0, 0, 0, 0, 0, 0};
    for (int m = 0; m < H2; ++m) {
      float w = W2[k * H2 + m];
      acc[0] = fmaf(w, nW[m * 2 + 0], acc[0]);
      acc[1] = fmaf(w, nW[m * 2 + 1], acc[1]);
      acc[2] = fmaf(w, eW[m * 2 + 0], acc[2]);
      acc[3] = fmaf(w, eW[m * 2 + 1], acc[3]);
      acc[4] = fmaf(w, eW[(H2 + m) * 2 + 0], acc[4]);
      acc[5] = fmaf(w, eW[(H2 + m) * 2 + 1], acc[5]);
    }
#pragma unroll
    for (int c = 0; c < 6; ++c) Wz8[k * 8 + c] = acc[c];
    Wz8[k * 8 + 6] = 0.0f; Wz8[k * 8 + 7] = 0.0f;
    if (k == 0) {
      float c0 = nb[0], c1 = nb[1], c2 = 0, c3 = 0, c4 = 0, c5 = 0;
      for (int m = 0; m < H2; ++m) {
        float bv = b2[m];
        c0 = fmaf(bv, nW[m * 2 + 0], c0);
        c1 = fmaf(bv, nW[m * 2 + 1], c1);
        c2 = fmaf(bv, eW[m * 2 + 0], c2);
        c3 = fmaf(bv, eW[m * 2 + 1], c3);
        c4 = fmaf(bv, eW[(H2 + m) * 2 + 0], c4);
        c5 = fmaf(bv, eW[(H2 + m) * 2 + 1], c5);
      }
      consts[0] = c0; consts[1] = c1; consts[2] = c2;
      consts[3] = c3; consts[4] = c4; consts[5] = c5;
      consts[6] = 0.0f; consts[7] = 0.0f;
    }
  }
}

// ---------------- degree histogram + per-edge rank (4 edges/thread) ----------------
__global__ void k_hist(const int* __restrict__ dst, int* __restrict__ hist,
                       unsigned short* __restrict__ rank, int E) {
  int i = blockIdx.x * blockDim.x + threadIdx.x;
  int e = i * 4;
  if (e + 3 < E) {
    int4 d4 = *(const int4*)(dst + e);
    int r0 = atomicAdd(&hist[d4.x], 1);
    int r1 = atomicAdd(&hist[d4.y], 1);
    int r2 = atomicAdd(&hist[d4.z], 1);
    int r3 = atomicAdd(&hist[d4.w], 1);
    unsigned pk0 = (unsigned)(r0 & 0xffff) | ((unsigned)(r1 & 0xffff) << 16);
    unsigned pk1 = (unsigned)(r2 & 0xffff) | ((unsigned)(r3 & 0xffff) << 16);
    *(unsigned*)(rank + e)     = pk0;
    *(unsigned*)(rank + e + 2) = pk1;
  } else {
    for (; e < E; ++e) {
      int r = atomicAdd(&hist[dst[e]], 1);
      rank[e] = (unsigned short)r;
    }
  }
}

// ---------------- scan phase 1 (+ fused dinv + last-block scan2) ----------------
__global__ void k_scan1(const int* __restrict__ hist, int* __restrict__ offs,
                        int* __restrict__ bsum, float* __restrict__ dinv,
                        int* __restrict__ bbase, int* __restrict__ done, int N) {
  __shared__ int ws[4];
  __shared__ int amLast;
  const int t = threadIdx.x;
  const int base = blockIdx.x * 1024 + t * 4;
  int4 v = make_int4(0, 0, 0, 0);
  if (base + 3 < N) v = *(const int4*)(hist + base);
  else {
    if (base + 0 < N) v.x = hist[base + 0];
    if (base + 1 < N) v.y = hist[base + 1];
    if (base + 2 < N) v.z = hist[base + 2];
    if (base + 3 < N) v.w = hist[base + 3];
  }
  if (base + 3 < N) {
    float4 dv = make_float4(rsqrtf((float)v.x + 1.0f), rsqrtf((float)v.y + 1.0f),
                            rsqrtf((float)v.z + 1.0f), rsqrtf((float)v.w + 1.0f));
    *(float4*)(dinv + base) = dv;
  } else {
    if (base + 0 < N) dinv[base + 0] = rsqrtf((float)v.x + 1.0f);
    if (base + 1 < N) dinv[base + 1] = rsqrtf((float)v.y + 1.0f);
    if (base + 2 < N) dinv[base + 2] = rsqrtf((float)v.z + 1.0f);
    if (base + 3 < N) dinv[base + 3] = rsqrtf((float)v.w + 1.0f);
  }
  int tsum = v.x + v.y + v.z + v.w;
  int lane = t & 63, wid = t >> 6;
  int incl = tsum;
#pragma unroll
  for (int off = 1; off < 64; off <<= 1) {
    int u = __shfl_up(incl, off);
    if (lane >= off) incl += u;
  }
  if (lane == 63) ws[wid] = incl;
  __syncthreads();
  int wbase = 0;
  for (int w = 0; w < wid; ++w) wbase += ws[w];
  int excl = wbase + incl - tsum;
  int4 o;
  o.x = excl;
  o.y = excl + v.x;
  o.z = excl + v.x + v.y;
  o.w = excl + v.x + v.y + v.z;
  if (base + 3 < N) *(int4*)(offs + base) = o;
  else {
    if (base + 0 < N) offs[base + 0] = o.x;
    if (base + 1 < N) offs[base + 1] = o.y;
    if (base + 2 < N) offs[base + 2] = o.z;
    if (base + 3 < N) offs[base + 3] = o.w;
  }
  if (t == 255) {
    bsum[blockIdx.x] = wbase + incl;
    __threadfence();
    amLast = (atomicAdd(done, 1) == (int)gridDim.x - 1) ? 1 : 0;
  }
  __syncthreads();
  if (amLast && t < 64) {
    int nb = (int)gridDim.x;
    int bv = (t < nb) ? atomicAdd(&bsum[t], 0) : 0;  // coherent read across XCDs
    int bincl = bv;
#pragma unroll
    for (int off = 1; off < 64; off <<= 1) {
      int u = __shfl_up(bincl, off);
      if (t >= off) bincl += u;
    }
    bbase[t] = bincl - bv;
    if (t == nb - 1) offs[N] = bv;
  }
}

// ---------------- CSR build: csr[pos] = (src<<16) | fp16(dinv[src]), 4 edges/thread ----------------
__global__ void k_build(const int* __restrict__ src, const int* __restrict__ dst,
                        const unsigned short* __restrict__ rank,
                        const int* __restrict__ offs, const int* __restrict__ bbase,
                        const float* __restrict__ dinv,
                        unsigned* __restrict__ csr, int E) {
  int i = blockIdx.x * blockDim.x + threadIdx.x;
  int e = i * 4;
  if (e + 3 < E) {
    int4 s4 = *(const int4*)(src + e);
    int4 d4 = *(const int4*)(dst + e);
    unsigned rr0 = *(const unsigned*)(rank + e);
    unsigned rr1 = *(const unsigned*)(rank + e + 2);
    int pos0 = offs[d4.x] + bbase[d4.x >> 10] + (int)(rr0 & 0xffffu);
    int pos1 = offs[d4.y] + bbase[d4.y >> 10] + (int)(rr0 >> 16);
    int pos2 = offs[d4.z] + bbase[d4.z >> 10] + (int)(rr1 & 0xffffu);
    int pos3 = offs[d4.w] + bbase[d4.w >> 10] + (int)(rr1 >> 16);
    unsigned v0 = ((unsigned)s4.x << 16) | f2h_bits(dinv[s4.x]);
    unsigned v1 = ((unsigned)s4.y << 16) | f2h_bits(dinv[s4.y]);
    unsigned v2 = ((unsigned)s4.z << 16) | f2h_bits(dinv[s4.z]);
    unsigned v3 = ((unsigned)s4.w << 16) | f2h_bits(dinv[s4.w]);
    csr[pos0] = v0;
    csr[pos1] = v1;
    csr[pos2] = v2;
    csr[pos3] = v3;
  } else {
    for (; e < E; ++e) {
      int s = src[e], d = dst[e];
      int pos = offs[d] + bbase[d >> 10] + (int)rank[e];
      csr[pos] = ((unsigned)s << 16) | f2h_bits(dinv[s]);
    }
  }
}

// ---------------- CSR gather C=64: 2 nodes/wave, 4-deep pipelined inner loop ----------------
__global__ __launch_bounds__(256) void
k_gather64(const int* __restrict__ offs, const int* __restrict__ bbase,
           const unsigned* __restrict__ csr, const float* __restrict__ dinv,
           const _Float16* __restrict__ xw, _Float16* __restrict__ out, int N) {
  constexpr int C = 64;
  int wave = (int)((blockIdx.x * (size_t)blockDim.x + threadIdx.x) >> 6);
  int lane = threadIdx.x & 63;
  int half = lane >> 5;
  int node = wave * 2 + half;
  if (node >= N) return;
  int l32   = lane & 31;
  int group = l32 >> 3;      // 4 edge-groups of 8 lanes
  int sub   = l32 & 7;
  int ch0   = sub * 8;
  int hb    = half << 5;
  float dv = dinv[node];
  int j0 = offs[node] + bbase[node >> 10];
  int j1 = offs[node + 1] + bbase[(node + 1) >> 10];

  float acc[8];
  if (group == 0) {
    half8 v = *(const half8*)(xw + (size_t)node * C + ch0);
    float sc = dv * dv;
#pragma unroll
    for (int k = 0; k < 8; ++k) acc[k] = (float)v[k] * sc;
  } else {
#pragma unroll
    for (int k = 0; k < 8; ++k) acc[k] = 0.0f;
  }

  for (int base = j0; base < j1; base += 32) {
    int myj = base + l32;
    unsigned u_l = (myj < j1) ? csr[myj] : 0u;
    int cnt = min(32, j1 - base);
    // 4-deep: each 8-lane group handles edges k+group, k+4+group, k+8+group, k+12+group
    for (int k = 0; k < cnt; k += 16) {
      unsigned u0 = (unsigned)__shfl((int)u_l, hb + k + group);
      unsigned u1 = (unsigned)__shfl((int)u_l, hb + k + 4 + group);
      unsigned u2 = (unsigned)__shfl((int)u_l, hb + k + 8 + group);
      unsigned u3 = (unsigned)__shfl((int)u_l, hb + k + 12 + group);
      half8 v0, v1, v2, v3;
      bool b0 = u0 != 0, b1 = u1 != 0, b2 = u2 != 0, b3 = u3 != 0;
      if (b0) v0 = *(const half8*)(xw + (size_t)(u0 >> 16) * C + ch0);
      if (b1) v1 = *(const half8*)(xw + (size_t)(u1 >> 16) * C + ch0);
      if (b2) v2 = *(const half8*)(xw + (size_t)(u2 >> 16) * C + ch0);
      if (b3) v3 = *(const half8*)(xw + (size_t)(u3 >> 16) * C + ch0);
      if (b0) {
        float c = h_bits2f(u0) * dv;
#pragma unroll
        for (int k2 = 0; k2 < 8; ++k2) acc[k2] = fmaf((float)v0[k2], c, acc[k2]);
      }
      if (b1) {
        float c = h_bits2f(u1) * dv;
#pragma unroll
        for (int k2 = 0; k2 < 8; ++k2) acc[k2] = fmaf((float)v1[k2], c, acc[k2]);
      }
      if (b2) {
        float c = h_bits2f(u2) * dv;
#pragma unroll
        for (int k2 = 0; k2 < 8; ++k2) acc[k2] = fmaf((float)v2[k2], c, acc[k2]);
      }
      if (b3) {
        float c = h_bits2f(u3) * dv;
#pragma unroll
        for (int k2 = 0; k2 < 8; ++k2) acc[k2] = fmaf((float)v3[k2], c, acc[k2]);
      }
    }
  }

#pragma unroll
  for (int off = 8; off < 32; off <<= 1) {
#pragma unroll
    for (int k = 0; k < 8; ++k) acc[k] += __shfl_xor(acc[k], off);
  }

  if (group == 0) {
    half8 o;
#pragma unroll
    for (int k = 0; k < 8; ++k) o[k] = (_Float16)acc[k];
    *(half8*)(out + (size_t)node * C + ch0) = o;
  }
}

// ---------------- fused MFMA GEMM + head projection (SWAPPED operands: D = h^T) ----------------
// acc[g][c] reg j = h[node = rowbase+g*16+(lane&15)][channel = c*16+kb*4+j]
__global__ __launch_bounds__(256) void
k_mgemm_z(const _Float16* __restrict__ A, const _Float16* __restrict__ Wf,
          const float* __restrict__ bias, const float* __restrict__ Wz8,
          float* __restrict__ z, int M) {
  constexpr int K = DIN, NOUT = H1;
  constexpr int NC = NOUT / 16;   // 16
  constexpr int NT = K / 32;      // 2
  const int wave = threadIdx.x >> 6;
  const int lane = threadIdx.x & 63;
  const int rowbase = blockIdx.x * 128 + wave * 32;
  if (rowbase >= M) return;
  const int r  = lane & 15;
  const int kb = lane >> 4;
  int row0 = rowbase + r;       if (row0 >= M) row0 = M - 1;
  int row1 = rowbase + 16 + r;  if (row1 >= M) row1 = M - 1;
  const _Float16* a0p = A + (size_t)row0 * K + kb * 8;
  const _Float16* a1p = A + (size_t)row1 * K + kb * 8;

  f32x4 acc[2][NC];
#pragma unroll
  for (int g = 0; g < 2; ++g)
#pragma unroll
    for (int c = 0; c < NC; ++c) acc[g][c] = (f32x4)0.0f;

#pragma unroll
  for (int t = 0; t < NT; ++t) {
    half8 a0 = *(const half8*)(a0p + t * 32);
    half8 a1 = *(const half8*)(a1p + t * 32);
#pragma unroll
    for (int c = 0; c < NC; ++c) {
      half8 bf = ((const half8*)Wf)[(size_t)(c * NT + t) * 64 + lane];
      // SWAP: A-operand = Wf (W1^T fragment), B-operand = node rows -> D = h^T
      acc[0][c] = __builtin_amdgcn_mfma_f32_16x16x32_f16(bf, a0, acc[0][c], 0, 0, 0);
      acc[1][c] = __builtin_amdgcn_mfma_f32_16x16x32_f16(bf, a1, acc[1][c], 0, 0, 0);
    }
  }

  // epilogue: lane owns node (rowbase + g*16 + r); channels c*16 + kb*4 + j
  float zc[2][6];
#pragma unroll
  for (int g = 0; g < 2; ++g)
#pragma unroll
    for (int ch = 0; ch < 6; ++ch) zc[g][ch] = 0.0f;

#pragma unroll
  for (int c = 0; c < NC; ++c) {
    float4 b4 = *(const float4*)(bias + c * 16 + kb * 4);
    float bj[4] = {b4.x, b4.y, b4.z, b4.w};
#pragma unroll
    for (int j = 0; j < 4; ++j) {
      const float* wp = Wz8 + (c * 16 + kb * 4 + j) * 8;
      float4 w0 = *(const float4*)wp;
      float2 w1 = *(const float2*)(wp + 4);
      float hv0 = fmaxf(acc[0][c][j] + bj[j], 0.0f);
      float hv1 = fmaxf(acc[1][c][j] + bj[j], 0.0f);
      zc[0][0] = fmaf(hv0, w0.x, zc[0][0]);
      zc[0][1] = fmaf(hv0, w0.y, zc[0][1]);
      zc[0][2] = fmaf(hv0, w0.z, zc[0][2]);
      zc[0][3] = fmaf(hv0, w0.w, zc[0][3]);
      zc[0][4] = fmaf(hv0, w1.x, zc[0][4]);
      zc[0][5] = fmaf(hv0, w1.y, zc[0][5]);
      zc[1][0] = fmaf(hv1, w0.x, zc[1][0]);
      zc[1][1] = fmaf(hv1, w0.y, zc[1][1]);
      zc[1][2] = fmaf(hv1, w0.z, zc[1][2]);
      zc[1][3] = fmaf(hv1, w0.w, zc[1][3]);
      zc[1][4] = fmaf(hv1, w1.x, zc[1][4]);
      zc[1][5] = fmaf(hv1, w1.y, zc[1][5]);
    }
  }

  // reduce over the 4 kb lane-groups (lanes r, r+16, r+32, r+48)
#pragma unroll
  for (int off = 16; off < 64; off <<= 1) {
#pragma unroll
    for (int g = 0; g < 2; ++g)
#pragma unroll
      for (int ch = 0; ch < 6; ++ch)
        zc[g][ch] += __shfl_xor(zc[g][ch], off);
  }

  if (lane < 16) {
#pragma unroll
    for (int g = 0; g < 2; ++g) {
      int grow = rowbase + g * 16 + r;
      if (grow < M) {
        float4 lo = make_float4(zc[g][0], zc[g][1], zc[g][2], zc[g][3]);
        float4 hi = make_float4(zc[g][4], zc[g][5], 0.0f, 0.0f);
        *(float4*)(z + (size_t)grow * 8)     = lo;
        *(float4*)(z + (size_t)grow * 8 + 4) = hi;
      }
    }
  }
}

// ---------------- aggregate z (C=8 fp32): 4 nodes/wave, 2-deep pipeline ----------------
__global__ __launch_bounds__(256) void
k_gatherz(const int* __restrict__ offs, const int* __restrict__ bbase,
          const unsigned* __restrict__ csr, const float* __restrict__ dinv,
          const float* __restrict__ z, const float* __restrict__ consts,
          float* __restrict__ node_out, float* __restrict__ p, float* __restrict__ q,
          int N) {
  int wave = (int)((blockIdx.x * (size_t)blockDim.x + threadIdx.x) >> 6);
  int lane = threadIdx.x & 63;
  int quad = lane >> 4;           // 0..3
  int node = wave * 4 + quad;
  if (node >= N) return;
  int l16   = lane & 15;
  int group = l16 >> 1;           // 8 edge-groups per node
  int sub   = l16 & 1;            // float4 half of the z row
  int hb    = quad << 4;
  float dv = dinv[node];
  int j0 = offs[node] + bbase[node >> 10];
  int j1 = offs[node + 1] + bbase[(node + 1) >> 10];

  float4 acc = make_float4(0.0f, 0.0f, 0.0f, 0.0f);
  if (group == 0) {
    float4 v = *(const float4*)(z + (size_t)node * 8 + sub * 4);
    float sc = dv * dv;
    acc = make_float4(v.x * sc, v.y * sc, v.z * sc, v.w * sc);
  }

  for (int base = j0; base < j1; base += 16) {
    int myj = base + l16;
    unsigned u_l = (myj < j1) ? csr[myj] : 0u;
    int cnt = min(16, j1 - base);
    for (int k = 0; k < cnt; k += 16) {
      unsigned u0 = (unsigned)__shfl((int)u_l, hb + k + group);
      unsigned u1 = (unsigned)__shfl((int)u_l, hb + k + 8 + group);
      float4 v0, v1;
      bool b0 = u0 != 0, b1 = u1 != 0;
      if (b0) v0 = *(const float4*)(z + (size_t)(u0 >> 16) * 8 + sub * 4);
      if (b1) v1 = *(const float4*)(z + (size_t)(u1 >> 16) * 8 + sub * 4);
      if (b0) {
        float c = h_bits2f(u0) * dv;
        acc.x = fmaf(v0.x, c, acc.x);
        acc.y = fmaf(v0.y, c, acc.y);
        acc.z = fmaf(v0.z, c, acc.z);
        acc.w = fmaf(v0.w, c, acc.w);
      }
      if (b1) {
        float c = h_bits2f(u1) * dv;
        acc.x = fmaf(v1.x, c, acc.x);
        acc.y = fmaf(v1.y, c, acc.y);
        acc.z = fmaf(v1.z, c, acc.z);
        acc.w = fmaf(v1.w, c, acc.w);
      }
    }
  }

#pragma unroll
  for (int off = 2; off < 16; off <<= 1) {
    acc.x += __shfl_xor(acc.x, off);
    acc.y += __shfl_xor(acc.y, off);
    acc.z += __shfl_xor(acc.z, off);
    acc.w += __shfl_xor(acc.w, off);
  }

  if (l16 == 0) {
    float2 no = make_float2(acc.x + consts[0], acc.y + consts[1]);
    float2 pp = make_float2(acc.z + consts[2], acc.w + consts[3]);
    *(float2*)(node_out + (size_t)node * 2) = no;
    *(float2*)(p + (size_t)node * 2) = pp;
  } else if (l16 == 1) {
    float2 qq = make_float2(acc.x + consts[4], acc.y + consts[5]);
    *(float2*)(q + (size_t)node * 2) = qq;
  }
}

// ---------------- edge output: 4 edges per thread ----------------
__global__ void k_edge(const int* __restrict__ src, const int* __restrict__ dst,
                       const float* __restrict__ p, const float* __restrict__ q,
                       const float* __restrict__ eb, float* __restrict__ eout, int E) {
  int i = blockIdx.x * blockDim.x + threadIdx.x;
  int e = i * 4;
  float e0 = eb[0], e1 = eb[1];
  if (e + 3 < E) {
    int4 s4 = *(const int4*)(src + e);
    int4 d4 = *(const int4*)(dst + e);
    float2 P0 = *(const float2*)(p + (size_t)s4.x * 2);
    float2 Q0 = *(const float2*)(q + (size_t)d4.x * 2);
    float2 P1 = *(const float2*)(p + (size_t)s4.y * 2);
    float2 Q1 = *(const float2*)(q + (size_t)d4.y * 2);
    float2 P2 = *(const float2*)(p + (size_t)s4.z * 2);
    float2 Q2 = *(const float2*)(q + (size_t)d4.z * 2);
    float2 P3 = *(const float2*)(p + (size_t)s4.w * 2);
    float2 Q3 = *(const float2*)(q + (size_t)d4.w * 2);
    float4 oa, ob;
    oa.x = P0.x + Q0.x + e0;  oa.y = P0.y + Q0.y + e1;
    oa.z = P1.x + Q1.x + e0;  oa.w = P1.y + Q1.y + e1;
    ob.x = P2.x + Q2.x + e0;  ob.y = P2.y + Q2.y + e1;
    ob.z = P3.x + Q3.x + e0;  ob.w = P3.y + Q3.y + e1;
    *(float4*)(eout + (size_t)e * 2)     = oa;
    *(float4*)(eout + (size_t)e * 2 + 4) = ob;
  } else {
    for (; e < E; ++e) {
      int s = src[e], d = dst[e];
      float2 P = *(const float2*)(p + (size_t)s * 2);
      float2 Q = *(const float2*)(q + (size_t)d * 2);
      float2 o;
      o.x = P.x + Q.x + e0;
      o.y = P.y + Q.y + e1;
      *(float2*)(eout + (size_t)e * 2) = o;
    }
  }
}

extern "C" void kernel_launch(void* const* d_in, const int* in_sizes, int n_in,
                              void* d_out, int out_size, void* d_ws, size_t ws_size,
                              hipStream_t stream) {
  const float* x   = (const float*)d_in[0];
  const int*   ei  = (const int*)d_in[1];
  const float* W1  = (const float*)d_in[2];
  const float* b1  = (const float*)d_in[3];
  const float* W2  = (const float*)d_in[4];
  const float* b2  = (const float*)d_in[5];
  const float* nW  = (const float*)d_in[6];
  const float* nb  = (const float*)d_in[7];
  const float* eW  = (const float*)d_in[8];
  const float* eb  = (const float*)d_in[9];

  const int N = in_sizes[0] / DIN;   // 50000
  const int E = in_sizes[1] / 2;     // 800000
  const int* src = ei;
  const int* dst = ei + E;

  // ---- workspace layout ----
  float* fws   = (float*)d_ws;
  float* dinv  = fws;                            // N
  float* p     = dinv + N;                       // 2N
  float* q     = p + 2 * (size_t)N;              // 2N
  float* z     = q + 2 * (size_t)N;              // 8N
  float* Wz8   = z + 8 * (size_t)N;              // 2048
  float* consts = Wz8 + 2048;                    // 8
  _Float16* xh    = (_Float16*)(consts + 8);     // 64N
  _Float16* aggxh = xh + (size_t)DIN * N;        // 64N
  _Float16* Wf1   = aggxh + (size_t)DIN * N;     // 16384
  int* hist = (int*)(Wf1 + DIN * H1);            // N
  int* offs = hist + N;                          // N+1
  int* bsum = offs + N + 1;                      // 64
  int* bbase = bsum + 64;                        // 64
  int* done  = bbase + 64;                       // 64 (only [0] used)
  unsigned short* rank = (unsigned short*)(done + 64);   // E (u16)
  unsigned* csr = (unsigned*)(rank + E);                 // E (u32 packed)

  float* node_out = (float*)d_out;                   // 2N
  float* edge_out = (float*)d_out + 2 * (size_t)N;   // 2E

  const int nb_blk = (N + 1023) / 1024;          // 49
  const int nvec8  = N * DIN / 8;

  const int NB0 = (N + 255) / 256;
  const int NB1 = NB0 + (nvec8 + 255) / 256;
  const int NB2 = NB1 + (DIN * H1 + 255) / 256;
  const int NBP = NB2 + 1;

  // ---- prep + CSR build ----
  k_prep<<<NBP, 256, 0, stream>>>(hist, N, x, xh, nvec8, W1, Wf1,
                                  W2, nW, nb, eW, b2, Wz8, consts, done, NB0, NB1, NB2);
  k_hist<<<((E + 3) / 4 + 255) / 256, 256, 0, stream>>>(dst, hist, rank, E);
  k_scan1<<<nb_blk, 256, 0, stream>>>(hist, offs, bsum, dinv, bbase, done, N);
  k_build<<<((E + 3) / 4 + 255) / 256, 256, 0, stream>>>(src, dst, rank, offs, bbase, dinv, csr, E);

  // ---- layer 1 aggregate, then fused transform + head projection ----
  {
    int waves = (N + 1) / 2;
    k_gather64<<<(waves + 3) / 4, 256, 0, stream>>>(offs, bbase, csr, dinv, xh, aggxh, N);
  }
  k_mgemm_z<<<(N + 127) / 128, 256, 0, stream>>>(aggxh, Wf1, b1, Wz8, z, N);

  // ---- aggregate 6-dim z -> node_out, p, q ----
  {
    int waves = (N + 3) / 4;
    k_gatherz<<<(waves + 3) / 4, 256, 0, stream>>>(offs, bbase, csr, dinv, z, consts, node_out, p, q, N);
  }

  // ---- edge output ----
  k_edge<<<((E + 3) / 4 + 255) / 256, 256, 0, stream>>>(src, dst, p, q, eb, edge_out, E);
}